// Round 10
// baseline (1223.618 us; speedup 1.0000x reference)
//
#include <hip/hip_runtime.h>

// x:              [B, C, N_OUT]  f32   (512 planes x 65536)
// idx_mask:       [B, C, N_OUT]  i32 in [0, K)
// sample_map:     [N_OUT, K, P]  i32 in [0, N_IN)
// interp_weights: [N_OUT, K, P]  f32
// out:            [B, C, N_IN]   f32
#define BB      8
#define CC      64
#define N_OUT   65536
#define N_IN    262144
#define KK      9
#define PP      4
#define NE      (N_OUT * KK * PP)   // 2,359,296
#define NPLANES 512
#define CHUNK   16                  // n per gather block (32 KB acc)
#define NCHUNKS (N_IN / CHUNK)      // 16384
#define NKEY    NCHUNKS
#define GTH     512                 // gather threads (8 waves)
#define NW      (GTH / 64)
#define NFB     128                 // fill/hist blocks
#define EPB     (NE / NFB)          // 18432
#define NQUART  4
#define CPQ     (NCHUNKS / NQUART)  // 4096 chunks per quarter
#define NPQ     (N_IN / NQUART)     // 65536 n per quarter

typedef float f4_t __attribute__((ext_vector_type(4)));

// ---------------- d_ws layout (int units) ----------------
// entries are int2: e.x = (o<<16)|(nl<<12)|((cnt-1)<<2) ; e.y = (w_bf16<<16)|start
#define WS_OFFSETS 0
#define WS_TOT     16400
#define WS_PRIV    32784
#define WS_HDR     (32784 + NFB * NKEY)           // 2129936
#define WS_ENTR    (2129936 + N_OUT * KK)         // 2719760 (8B aligned)
#define WS_XK      (2719760 + 2 * NE)             // 7438352
#define WS_STG     (7438352 + N_OUT * 512)        // 40992784  (~156.4 MiB up to here)
#define WS_END_B   WS_STG
#define WS_END_A   (WS_STG + NPQ * NPLANES)       // 74547216 ints (~284.4 MiB)

// ============================================================================
// k_xk: per o, sort the 512 planes' x by their idx_mask tap k.
//   xk[o][j] (k-sorted) = (x_bits & 0xFFFFFE00) | plane_id (9 bits)
//   hdr[o*9+k] = start | (cnt << 16)
// ============================================================================
#define XKTILE 16
#define XPAD   520
__global__ __launch_bounds__(256) void k_xk(const float* __restrict__ x,
                                            const int*   __restrict__ idx,
                                            unsigned* __restrict__ xk,
                                            unsigned* __restrict__ hdr) {
    __shared__ float xs[XKTILE * XPAD];
    __shared__ unsigned char ks[XKTILE * XPAD];
    __shared__ unsigned ot[XKTILE * 512];
    __shared__ int cnt[XKTILE][12];
    __shared__ int cur[XKTILE][12];
    const int t = threadIdx.x;
    const int obase = blockIdx.x * XKTILE;

    for (int i = t; i < XKTILE * 12; i += 256) cnt[i / 12][i % 12] = 0;

    for (int i = t; i < 512 * (XKTILE / 4); i += 256) {
        int p = i >> 2, q = i & 3;
        const size_t g = (size_t)p * N_OUT + obase + 4 * q;
        float4 xv = *(const float4*)(x + g);
        int4   kv = *(const int4*)(idx + g);
        int b = (4 * q) * XPAD + p;
        xs[b] = xv.x; xs[b + XPAD] = xv.y; xs[b + 2 * XPAD] = xv.z; xs[b + 3 * XPAD] = xv.w;
        ks[b] = (unsigned char)kv.x; ks[b + XPAD] = (unsigned char)kv.y;
        ks[b + 2 * XPAD] = (unsigned char)kv.z; ks[b + 3 * XPAD] = (unsigned char)kv.w;
    }
    __syncthreads();
    for (int i = t; i < XKTILE * 512; i += 256) {
        int oo = i >> 9, p = i & 511;
        atomicAdd(&cnt[oo][ks[oo * XPAD + p]], 1);
    }
    __syncthreads();
    if (t < XKTILE) {
        int s = 0;
        for (int k = 0; k < KK; ++k) {
            int c = cnt[t][k];
            cur[t][k] = s;
            hdr[(size_t)(obase + t) * KK + k] = (unsigned)(s | (c << 16));
            s += c;
        }
    }
    __syncthreads();
    for (int i = t; i < XKTILE * 512; i += 256) {
        int oo = i >> 9, p = i & 511;
        int k = ks[oo * XPAD + p];
        int pos = atomicAdd(&cur[oo][k], 1);
        unsigned xb = __float_as_uint(xs[oo * XPAD + p]);
        ot[(oo << 9) + pos] = (xb & 0xFFFFFE00u) | (unsigned)p;
    }
    __syncthreads();
    for (int i = t; i < XKTILE * 128; i += 256) {
        int oo = i >> 7, c4 = i & 127;
        ((int4*)(xk + (((size_t)(obase + oo)) << 9)))[c4] = ((const int4*)(ot + (oo << 9)))[c4];
    }
}

// ============================================================================
// Build: deterministic counting sort over 16384 chunk keys, no global atomics.
// ============================================================================
__global__ __launch_bounds__(1024) void k_histA(const int* __restrict__ smap,
                                                int* __restrict__ priv) {
    __shared__ int h[NKEY];
    const int b = blockIdx.x;
    const int t = threadIdx.x;
    for (int i = t; i < NKEY; i += 1024) h[i] = 0;
    __syncthreads();
    const int e0 = b * EPB;
    #pragma unroll 2
    for (int i = 0; i < EPB / 1024; ++i)
        atomicAdd(&h[smap[e0 + i * 1024 + t] >> 4], 1);
    __syncthreads();
    for (int i = t; i < NKEY; i += 1024) priv[b * NKEY + i] = h[i];
}

__global__ __launch_bounds__(1024) void k_colscan(int* __restrict__ priv,
                                                  int* __restrict__ tot) {
    const int key = blockIdx.x * 1024 + threadIdx.x;
    int run = 0;
    for (int b = 0; b < NFB; ++b) {
        int* p = priv + b * NKEY + key;
        int v = *p; *p = run; run += v;
    }
    tot[key] = run;
}

__global__ __launch_bounds__(1024) void k_scan16k(const int* __restrict__ tot,
                                                  int* __restrict__ offsets) {
    __shared__ int sw[1024];
    const int t = threadIdx.x;
    int4 q0 = ((const int4*)tot)[4 * t + 0];
    int4 q1 = ((const int4*)tot)[4 * t + 1];
    int4 q2 = ((const int4*)tot)[4 * t + 2];
    int4 q3 = ((const int4*)tot)[4 * t + 3];
    int vals[16] = {q0.x, q0.y, q0.z, q0.w, q1.x, q1.y, q1.z, q1.w,
                    q2.x, q2.y, q2.z, q2.w, q3.x, q3.y, q3.z, q3.w};
    int s = 0;
    #pragma unroll
    for (int i = 0; i < 16; ++i) s += vals[i];
    sw[t] = s;
    __syncthreads();
    for (int off = 1; off < 1024; off <<= 1) {
        int v = (t >= off) ? sw[t - off] : 0;
        __syncthreads();
        sw[t] += v;
        __syncthreads();
    }
    int run = sw[t] - s;
    int o[16];
    #pragma unroll
    for (int i = 0; i < 16; ++i) { o[i] = run; run += vals[i]; }
    ((int4*)offsets)[4 * t + 0] = make_int4(o[0], o[1], o[2], o[3]);
    ((int4*)offsets)[4 * t + 1] = make_int4(o[4], o[5], o[6], o[7]);
    ((int4*)offsets)[4 * t + 2] = make_int4(o[8], o[9], o[10], o[11]);
    ((int4*)offsets)[4 * t + 3] = make_int4(o[12], o[13], o[14], o[15]);
    if (t == 1023) offsets[NKEY] = NE;
}

// fill 8-byte entries at deterministic bases
__global__ __launch_bounds__(1024) void k_fillB(const int* __restrict__ smap,
                                                const float* __restrict__ wts,
                                                const int* __restrict__ priv,
                                                const int* __restrict__ offsets,
                                                const unsigned* __restrict__ hdr,
                                                int2* __restrict__ entries) {
    __shared__ int cur[NKEY];
    const int b = blockIdx.x;
    const int t = threadIdx.x;
    for (int i = t; i < NKEY; i += 1024) cur[i] = offsets[i] + priv[b * NKEY + i];
    __syncthreads();
    const int e0 = b * EPB;
    for (int i = 0; i < EPB / 1024; ++i) {      // 18
        const int e = e0 + i * 1024 + t;
        const int n = smap[e];
        const int o = e / 36;                   // e = o*36 + k*4 + p_tap
        const int r = e - o * 36;
        const int k = r >> 2;
        const unsigned h = hdr[(size_t)o * KK + k];
        const int st = (int)(h & 0xFFFFu);
        const int cn = (int)(h >> 16);          // 1..512
        const unsigned wb = (__float_as_uint(wts[e]) + 0x8000u) >> 16;  // bf16 rn
        const int pos = atomicAdd(&cur[n >> 4], 1);
        entries[pos] = make_int2((o << 16) | ((n & 15) << 12) | ((cn - 1) << 2),
                                 (int)((wb << 16) | (unsigned)st));
    }
}

// ---------- entry decode ----------
#define DECODE(e, o, nl, cn, st, w)                         \
    const int o  = ((unsigned)(e).x) >> 16;                 \
    const int nl = ((e).x >> 12) & 15;                      \
    const int cn = (((e).x >> 2) & 511) + 1;                \
    const int st = (e).y & 511;                             \
    const float w = __uint_as_float(((unsigned)(e).y >> 16) << 16);

// ============================================================================
// Staged gather: block = one 16-n chunk x 512 planes; acc linear [16][512].
// Flush = 32 KB CONTIGUOUS nontemporal stream into outT[n - q*65536][p]
// -> output writes bypass L2/L3, keeping xk (128 MB) + entries L3-resident.
// ============================================================================
__global__ __launch_bounds__(GTH, 8) void k_gather_stg(const int* __restrict__ offsets,
                                                       const int2* __restrict__ entries,
                                                       const unsigned* __restrict__ xk,
                                                       float* __restrict__ outT, int c0) {
    __shared__ float acc[CHUNK * NPLANES];       // 32 KB
    const int bid = blockIdx.x;
    const int c = c0 + ((bid & 7) << 9) + (bid >> 3);   // XCD-contiguous in quarter

    const int tid = threadIdx.x;
    const int lane = tid & 63;
    const int wid = tid >> 6;

    f4_t* a4 = (f4_t*)acc;
    for (int i = tid; i < CHUNK * NPLANES / 4; i += GTH) a4[i] = (f4_t){0.f, 0.f, 0.f, 0.f};
    __syncthreads();

    const int j1 = offsets[c + 1];
    int jA = offsets[c] + wid;

    int2 eA0 = {0, 0}, eA1 = {0, 0};
    if (jA < j1)      eA0 = entries[jA];
    if (jA + NW < j1) eA1 = entries[jA + NW];
    unsigned xA0 = 0, xA1 = 0, xA0b = 0, xA1b = 0;
    if (jA < j1) {
        DECODE(eA0, o, nl, cn, st, w)
        const unsigned* r = xk + ((size_t)o << 9) + st;
        if (lane < cn) xA0 = r[lane];
        if (cn > 64 && lane + 64 < cn) xA0b = r[lane + 64];
    }
    if (jA + NW < j1) {
        DECODE(eA1, o, nl, cn, st, w)
        const unsigned* r = xk + ((size_t)o << 9) + st;
        if (lane < cn) xA1 = r[lane];
        if (cn > 64 && lane + 64 < cn) xA1b = r[lane + 64];
    }
    int jB = jA + 2 * NW;
    int2 eB0 = {0, 0}, eB1 = {0, 0};
    if (jB < j1)      eB0 = entries[jB];
    if (jB + NW < j1) eB1 = entries[jB + NW];

    while (jA < j1) {
        unsigned xB0 = 0, xB1 = 0, xB0b = 0, xB1b = 0;
        if (jB < j1) {
            DECODE(eB0, o, nl, cn, st, w)
            const unsigned* r = xk + ((size_t)o << 9) + st;
            if (lane < cn) xB0 = r[lane];
            if (cn > 64 && lane + 64 < cn) xB0b = r[lane + 64];
        }
        if (jB + NW < j1) {
            DECODE(eB1, o, nl, cn, st, w)
            const unsigned* r = xk + ((size_t)o << 9) + st;
            if (lane < cn) xB1 = r[lane];
            if (cn > 64 && lane + 64 < cn) xB1b = r[lane + 64];
        }
        const int jC = jB + 2 * NW;
        int2 eC0 = {0, 0}, eC1 = {0, 0};
        if (jC < j1)      eC0 = entries[jC];
        if (jC + NW < j1) eC1 = entries[jC + NW];

        if (jA < j1) {
            DECODE(eA0, o, nl, cn, st, w)
            if (lane < cn)
                atomicAdd(&acc[(nl << 9) + (int)(xA0 & 511)], w * __uint_as_float(xA0 & 0xFFFFFE00u));
            if (cn > 64 && lane + 64 < cn)
                atomicAdd(&acc[(nl << 9) + (int)(xA0b & 511)], w * __uint_as_float(xA0b & 0xFFFFFE00u));
            if (cn > 128) {
                const unsigned* r = xk + ((size_t)o << 9) + st;
                for (int b = lane + 128; b < cn; b += 64) {
                    unsigned u = r[b];
                    atomicAdd(&acc[(nl << 9) + (int)(u & 511)], w * __uint_as_float(u & 0xFFFFFE00u));
                }
            }
        }
        if (jA + NW < j1) {
            DECODE(eA1, o, nl, cn, st, w)
            if (lane < cn)
                atomicAdd(&acc[(nl << 9) + (int)(xA1 & 511)], w * __uint_as_float(xA1 & 0xFFFFFE00u));
            if (cn > 64 && lane + 64 < cn)
                atomicAdd(&acc[(nl << 9) + (int)(xA1b & 511)], w * __uint_as_float(xA1b & 0xFFFFFE00u));
            if (cn > 128) {
                const unsigned* r = xk + ((size_t)o << 9) + st;
                for (int b = lane + 128; b < cn; b += 64) {
                    unsigned u = r[b];
                    atomicAdd(&acc[(nl << 9) + (int)(u & 511)], w * __uint_as_float(u & 0xFFFFFE00u));
                }
            }
        }
        eA0 = eB0; eA1 = eB1;
        xA0 = xB0; xA1 = xB1; xA0b = xB0b; xA1b = xB1b;
        jA = jB;
        eB0 = eC0; eB1 = eC1; jB = jC;
    }
    __syncthreads();

    // contiguous 32 KB nontemporal flush: outT[(c-c0)*16 + nl][p]
    f4_t* dst = (f4_t*)outT + ((size_t)(c - c0) << 4) * (NPLANES / 4);
    const f4_t* af = (const f4_t*)acc;
    for (int i = tid; i < CHUNK * NPLANES / 4; i += GTH)
        __builtin_nontemporal_store(af[i], dst + i);
}

// ============================================================================
// Transpose quarter: outT[65536][512] -> out[512][nbase+65536).
// Tile 512n x 32p (66 KB LDS). Reads 128 B coalesced lines; writes 1 KB
// contiguous NT bursts per wave.
// ============================================================================
__global__ __launch_bounds__(512) void k_transp(const float* __restrict__ outT,
                                                float* __restrict__ out, int nbase) {
    __shared__ float tile[512 * 33];             // 66 KB
    const int bn = blockIdx.x & 127;             // n-tile (512 wide)
    const int bp = blockIdx.x >> 7;              // p-tile (32 wide)
    const int t = threadIdx.x;

    #pragma unroll
    for (int it = 0; it < 8; ++it) {
        const int i = it * 512 + t;
        const int r = i >> 3;                    // 0..511
        const int c4 = i & 7;                    // 0..7 (x4 floats)
        f4_t v = *(const f4_t*)(outT + ((size_t)(bn * 512 + r) << 9) + bp * 32 + c4 * 4);
        const int b = r * 33 + c4 * 4;
        tile[b] = v.x; tile[b + 1] = v.y; tile[b + 2] = v.z; tile[b + 3] = v.w;
    }
    __syncthreads();

    #pragma unroll
    for (int it = 0; it < 8; ++it) {
        const int i = it * 512 + t;
        const int pr = i >> 7;                   // 0..31
        const int n4 = i & 127;                  // 0..127 (x4 n)
        f4_t v;
        v.x = tile[(n4 * 4 + 0) * 33 + pr];
        v.y = tile[(n4 * 4 + 1) * 33 + pr];
        v.z = tile[(n4 * 4 + 2) * 33 + pr];
        v.w = tile[(n4 * 4 + 3) * 33 + pr];
        f4_t* dst = (f4_t*)(out + (size_t)(bp * 32 + pr) * N_IN + nbase + bn * 512 + n4 * 4);
        __builtin_nontemporal_store(v, dst);
    }
}

// ============================================================================
// Tier B: direct-out gather (round-9 structure, 8-byte entries).
// ============================================================================
#define SWZ(p, nl) ((p) ^ ((nl) << 1))
__global__ __launch_bounds__(GTH, 8) void k_gather_dir(const int* __restrict__ offsets,
                                                       const int2* __restrict__ entries,
                                                       const unsigned* __restrict__ xk,
                                                       float* __restrict__ out) {
    __shared__ float acc[CHUNK * NPLANES];
    const int bid = blockIdx.x;
    const int c = (bid & 7) * (NCHUNKS / 8) + (bid >> 3);
    const int tid = threadIdx.x;
    const int lane = tid & 63;
    const int wid = tid >> 6;

    f4_t* a4 = (f4_t*)acc;
    for (int i = tid; i < CHUNK * NPLANES / 4; i += GTH) a4[i] = (f4_t){0.f, 0.f, 0.f, 0.f};
    __syncthreads();

    const int j1 = offsets[c + 1];
    int jA = offsets[c] + wid;
    int2 eA0 = {0, 0}, eA1 = {0, 0};
    if (jA < j1)      eA0 = entries[jA];
    if (jA + NW < j1) eA1 = entries[jA + NW];
    unsigned xA0 = 0, xA1 = 0, xA0b = 0, xA1b = 0;
    if (jA < j1) {
        DECODE(eA0, o, nl, cn, st, w)
        const unsigned* r = xk + ((size_t)o << 9) + st;
        if (lane < cn) xA0 = r[lane];
        if (cn > 64 && lane + 64 < cn) xA0b = r[lane + 64];
    }
    if (jA + NW < j1) {
        DECODE(eA1, o, nl, cn, st, w)
        const unsigned* r = xk + ((size_t)o << 9) + st;
        if (lane < cn) xA1 = r[lane];
        if (cn > 64 && lane + 64 < cn) xA1b = r[lane + 64];
    }
    int jB = jA + 2 * NW;
    int2 eB0 = {0, 0}, eB1 = {0, 0};
    if (jB < j1)      eB0 = entries[jB];
    if (jB + NW < j1) eB1 = entries[jB + NW];

    while (jA < j1) {
        unsigned xB0 = 0, xB1 = 0, xB0b = 0, xB1b = 0;
        if (jB < j1) {
            DECODE(eB0, o, nl, cn, st, w)
            const unsigned* r = xk + ((size_t)o << 9) + st;
            if (lane < cn) xB0 = r[lane];
            if (cn > 64 && lane + 64 < cn) xB0b = r[lane + 64];
        }
        if (jB + NW < j1) {
            DECODE(eB1, o, nl, cn, st, w)
            const unsigned* r = xk + ((size_t)o << 9) + st;
            if (lane < cn) xB1 = r[lane];
            if (cn > 64 && lane + 64 < cn) xB1b = r[lane + 64];
        }
        const int jC = jB + 2 * NW;
        int2 eC0 = {0, 0}, eC1 = {0, 0};
        if (jC < j1)      eC0 = entries[jC];
        if (jC + NW < j1) eC1 = entries[jC + NW];

        if (jA < j1) {
            DECODE(eA0, o, nl, cn, st, w)
            if (lane < cn) {
                int p = xA0 & 511;
                atomicAdd(&acc[(nl << 9) + SWZ(p, nl)], w * __uint_as_float(xA0 & 0xFFFFFE00u));
            }
            if (cn > 64 && lane + 64 < cn) {
                int p = xA0b & 511;
                atomicAdd(&acc[(nl << 9) + SWZ(p, nl)], w * __uint_as_float(xA0b & 0xFFFFFE00u));
            }
            if (cn > 128) {
                const unsigned* r = xk + ((size_t)o << 9) + st;
                for (int b = lane + 128; b < cn; b += 64) {
                    unsigned u = r[b];
                    int p = u & 511;
                    atomicAdd(&acc[(nl << 9) + SWZ(p, nl)], w * __uint_as_float(u & 0xFFFFFE00u));
                }
            }
        }
        if (jA + NW < j1) {
            DECODE(eA1, o, nl, cn, st, w)
            if (lane < cn) {
                int p = xA1 & 511;
                atomicAdd(&acc[(nl << 9) + SWZ(p, nl)], w * __uint_as_float(xA1 & 0xFFFFFE00u));
            }
            if (cn > 64 && lane + 64 < cn) {
                int p = xA1b & 511;
                atomicAdd(&acc[(nl << 9) + SWZ(p, nl)], w * __uint_as_float(xA1b & 0xFFFFFE00u));
            }
            if (cn > 128) {
                const unsigned* r = xk + ((size_t)o << 9) + st;
                for (int b = lane + 128; b < cn; b += 64) {
                    unsigned u = r[b];
                    int p = u & 511;
                    atomicAdd(&acc[(nl << 9) + SWZ(p, nl)], w * __uint_as_float(u & 0xFFFFFE00u));
                }
            }
        }
        eA0 = eB0; eA1 = eB1;
        xA0 = xB0; xA1 = xB1; xA0b = xB0b; xA1b = xB1b;
        jA = jB;
        eB0 = eC0; eB1 = eC1; jB = jC;
    }
    __syncthreads();

    const int n0 = c << 4;
    for (int i = tid; i < CHUNK * NPLANES / 4; i += GTH) {
        const int p = i >> 2;
        const int nl = (i & 3) << 2;
        float4 v;
        v.x = acc[((nl + 0) << 9) + SWZ(p, nl + 0)];
        v.y = acc[((nl + 1) << 9) + SWZ(p, nl + 1)];
        v.z = acc[((nl + 2) << 9) + SWZ(p, nl + 2)];
        v.w = acc[((nl + 3) << 9) + SWZ(p, nl + 3)];
        *(float4*)(out + (size_t)p * N_IN + n0 + nl) = v;
    }
}

// ============================================================================
// Fallback (ws too small): atomic scatter
// ============================================================================
__global__ __launch_bounds__(256) void zero_kernel(float4* __restrict__ out, int n4) {
    int i = blockIdx.x * blockDim.x + threadIdx.x;
    int stride = gridDim.x * blockDim.x;
    const float4 z = {0.f, 0.f, 0.f, 0.f};
    for (; i < n4; i += stride) out[i] = z;
}

__global__ __launch_bounds__(256) void scatter_kernel(
    const float* __restrict__ x, const int* __restrict__ idx_mask,
    const int4* __restrict__ smap, const float4* __restrict__ wts,
    float* __restrict__ out)
{
    const int plane = blockIdx.x >> 8;
    const int o = ((blockIdx.x & 255) << 8) + threadIdx.x;
    const long ibase = (long)plane * N_OUT + o;
    const float xv = x[ibase];
    const int k = idx_mask[ibase];
    const int row = o * KK + k;
    const int4 m = smap[row];
    const float4 w = wts[row];
    float* op = out + (long)plane * N_IN;
    atomicAdd(op + m.x, w.x * xv);
    atomicAdd(op + m.y, w.y * xv);
    atomicAdd(op + m.z, w.z * xv);
    atomicAdd(op + m.w, w.w * xv);
}

// ============================================================================
extern "C" void kernel_launch(void* const* d_in, const int* in_sizes, int n_in,
                              void* d_out, int out_size, void* d_ws, size_t ws_size,
                              hipStream_t stream) {
    const float* x    = (const float*)d_in[0];
    const int*   idx  = (const int*)d_in[1];
    const int*   smap = (const int*)d_in[2];
    const float* wts  = (const float*)d_in[3];
    float* out = (float*)d_out;

    if (ws_size < (size_t)WS_END_B * 4) {
        zero_kernel<<<4096, 256, 0, stream>>>((float4*)out, out_size / 4);
        scatter_kernel<<<NPLANES * (N_OUT / 256), 256, 0, stream>>>(
            x, idx, (const int4*)smap, (const float4*)wts, out);
        return;
    }

    int* ws = (int*)d_ws;
    int* offsets   = ws + WS_OFFSETS;
    int* tot       = ws + WS_TOT;
    int* priv      = ws + WS_PRIV;
    unsigned* hdr  = (unsigned*)(ws + WS_HDR);
    int2* entries  = (int2*)(ws + WS_ENTR);
    unsigned* xk   = (unsigned*)(ws + WS_XK);
    float* stg     = (float*)(ws + WS_STG);

    // build
    k_xk<<<N_OUT / XKTILE, 256, 0, stream>>>(x, idx, xk, hdr);
    k_histA<<<NFB, 1024, 0, stream>>>(smap, priv);
    k_colscan<<<16, 1024, 0, stream>>>(priv, tot);
    k_scan16k<<<1, 1024, 0, stream>>>(tot, offsets);
    k_fillB<<<NFB, 1024, 0, stream>>>(smap, wts, priv, offsets, hdr, entries);

    if (ws_size >= (size_t)WS_END_A * 4) {
        // staged path: 4 x (gather quarter -> transpose quarter)
        for (int q = 0; q < NQUART; ++q) {
            k_gather_stg<<<CPQ, GTH, 0, stream>>>(offsets, entries, xk, stg, q * CPQ);
            k_transp<<<2048, 512, 0, stream>>>(stg, out, q * NPQ);
        }
    } else {
        k_gather_dir<<<NCHUNKS, GTH, 0, stream>>>(offsets, entries, xk, out);
    }
}

// Round 11
// 1046.512 us; speedup vs baseline: 1.1692x; 1.1692x over previous
//
#include <hip/hip_runtime.h>

// x:              [B, C, N_OUT]  f32   (512 planes x 65536)
// idx_mask:       [B, C, N_OUT]  i32 in [0, K)
// sample_map:     [N_OUT, K, P]  i32 in [0, N_IN)
// interp_weights: [N_OUT, K, P]  f32
// out:            [B, C, N_IN]   f32
#define BB      8
#define CC      64
#define N_OUT   65536
#define N_IN    262144
#define KK      9
#define PP      4
#define NE      (N_OUT * KK * PP)   // 2,359,296
#define NPLANES 512
#define CHUNK   16                  // n per gather block (32 KB acc)
#define NCHUNKS (N_IN / CHUNK)      // 16384
#define NKEY    NCHUNKS
#define GTH     512                 // gather threads (8 waves, 16 half-wave streams)
#define NS      (GTH / 32)          // 16 entry streams per block
#define NFB     128                 // fill/hist blocks
#define EPB     (NE / NFB)          // 18432
#define XSTRIDE 800                 // u32 per xk row (25 x 128B, runs 128B-aligned)

typedef float f4_t __attribute__((ext_vector_type(4)));

// ---------------- d_ws layout (int units) ----------------
// entries int2: e.x = (o<<16)|(nl<<12)|((cnt-1)<<2) ; e.y = (w_bf16<<16)|start
// xk rows: stride 800 u32; each (o,k) run starts at a 32-u32 (128B) boundary.
#define WS_OFFSETS 0
#define WS_TOT     16400
#define WS_PRIV    32784
#define WS_HDR     (32784 + NFB * NKEY)           // 2129936
#define WS_ENTR    (2129936 + N_OUT * KK)         // 2719760
#define WS_XK      (((2719760 + 2 * NE) + 31) & ~31)   // 7438368 (128B aligned)
#define WS_END     (WS_XK + N_OUT * XSTRIDE)      // 59,867,168 ints (~228 MiB)

// ============================================================================
// k_xk: per o, sort the 512 planes' x by idx_mask tap k into PADDED runs.
//   xk[o*800 + padded_pos] = (x_bits & 0xFFFFFE00) | plane_id (9 bits)
//   hdr[o*9+k] = padded_start | (cnt << 16)      (padded_start <= 791)
// ============================================================================
#define XKTILE 16
#define XPAD   520
__global__ __launch_bounds__(256) void k_xk(const float* __restrict__ x,
                                            const int*   __restrict__ idx,
                                            unsigned* __restrict__ xk,
                                            unsigned* __restrict__ hdr) {
    __shared__ float xs[XKTILE * XPAD];          // 33.3 KB
    __shared__ unsigned char ks[XKTILE * XPAD];  // 8.3 KB
    __shared__ unsigned ot[XKTILE * 512];        // 32 KB compact tile
    __shared__ int cnt[XKTILE][12];
    __shared__ int cur[XKTILE][12];
    __shared__ int cstart[XKTILE][12];           // compact run starts (+sentinel)
    __shared__ int pstart[XKTILE][12];           // padded run starts
    const int t = threadIdx.x;
    const int obase = blockIdx.x * XKTILE;

    for (int i = t; i < XKTILE * 12; i += 256) cnt[i / 12][i % 12] = 0;

    for (int i = t; i < 512 * (XKTILE / 4); i += 256) {
        int p = i >> 2, q = i & 3;
        const size_t g = (size_t)p * N_OUT + obase + 4 * q;
        float4 xv = *(const float4*)(x + g);
        int4   kv = *(const int4*)(idx + g);
        int b = (4 * q) * XPAD + p;
        xs[b] = xv.x; xs[b + XPAD] = xv.y; xs[b + 2 * XPAD] = xv.z; xs[b + 3 * XPAD] = xv.w;
        ks[b] = (unsigned char)kv.x; ks[b + XPAD] = (unsigned char)kv.y;
        ks[b + 2 * XPAD] = (unsigned char)kv.z; ks[b + 3 * XPAD] = (unsigned char)kv.w;
    }
    __syncthreads();
    for (int i = t; i < XKTILE * 512; i += 256) {
        int oo = i >> 9, p = i & 511;
        atomicAdd(&cnt[oo][ks[oo * XPAD + p]], 1);
    }
    __syncthreads();
    if (t < XKTILE) {
        int s = 0, sp = 0;
        for (int k = 0; k < KK; ++k) {
            int c = cnt[t][k];
            cstart[t][k] = s;
            cur[t][k] = s;
            pstart[t][k] = sp;
            hdr[(size_t)(obase + t) * KK + k] = (unsigned)(sp | (c << 16));
            s += c;
            sp += (c + 31) & ~31;
        }
        cstart[t][KK] = 512;                     // sentinel
    }
    __syncthreads();
    for (int i = t; i < XKTILE * 512; i += 256) {
        int oo = i >> 9, p = i & 511;
        int k = ks[oo * XPAD + p];
        int pos = atomicAdd(&cur[oo][k], 1);
        unsigned xb = __float_as_uint(xs[oo * XPAD + p]);
        ot[(oo << 9) + pos] = (xb & 0xFFFFFE00u) | (unsigned)p;
    }
    __syncthreads();
    // flush compact -> padded (coalesced within runs; padding holes untouched)
    for (int i = t; i < XKTILE * 512; i += 256) {
        int oo = i >> 9, pos = i & 511;
        int k = 0;
        while (k < KK - 1 && pos >= cstart[oo][k + 1]) ++k;
        int dst = pstart[oo][k] + (pos - cstart[oo][k]);
        xk[(size_t)(obase + oo) * XSTRIDE + dst] = ot[(oo << 9) + pos];
    }
}

// ============================================================================
// Build: deterministic counting sort over 16384 chunk keys, no global atomics.
// ============================================================================
__global__ __launch_bounds__(1024) void k_histA(const int* __restrict__ smap,
                                                int* __restrict__ priv) {
    __shared__ int h[NKEY];
    const int b = blockIdx.x;
    const int t = threadIdx.x;
    for (int i = t; i < NKEY; i += 1024) h[i] = 0;
    __syncthreads();
    const int e0 = b * EPB;
    #pragma unroll 2
    for (int i = 0; i < EPB / 1024; ++i)
        atomicAdd(&h[smap[e0 + i * 1024 + t] >> 4], 1);
    __syncthreads();
    for (int i = t; i < NKEY; i += 1024) priv[b * NKEY + i] = h[i];
}

__global__ __launch_bounds__(1024) void k_colscan(int* __restrict__ priv,
                                                  int* __restrict__ tot) {
    const int key = blockIdx.x * 1024 + threadIdx.x;
    int run = 0;
    for (int b = 0; b < NFB; ++b) {
        int* p = priv + b * NKEY + key;
        int v = *p; *p = run; run += v;
    }
    tot[key] = run;
}

__global__ __launch_bounds__(1024) void k_scan16k(const int* __restrict__ tot,
                                                  int* __restrict__ offsets) {
    __shared__ int sw[1024];
    const int t = threadIdx.x;
    int4 q0 = ((const int4*)tot)[4 * t + 0];
    int4 q1 = ((const int4*)tot)[4 * t + 1];
    int4 q2 = ((const int4*)tot)[4 * t + 2];
    int4 q3 = ((const int4*)tot)[4 * t + 3];
    int vals[16] = {q0.x, q0.y, q0.z, q0.w, q1.x, q1.y, q1.z, q1.w,
                    q2.x, q2.y, q2.z, q2.w, q3.x, q3.y, q3.z, q3.w};
    int s = 0;
    #pragma unroll
    for (int i = 0; i < 16; ++i) s += vals[i];
    sw[t] = s;
    __syncthreads();
    for (int off = 1; off < 1024; off <<= 1) {
        int v = (t >= off) ? sw[t - off] : 0;
        __syncthreads();
        sw[t] += v;
        __syncthreads();
    }
    int run = sw[t] - s;
    int o[16];
    #pragma unroll
    for (int i = 0; i < 16; ++i) { o[i] = run; run += vals[i]; }
    ((int4*)offsets)[4 * t + 0] = make_int4(o[0], o[1], o[2], o[3]);
    ((int4*)offsets)[4 * t + 1] = make_int4(o[4], o[5], o[6], o[7]);
    ((int4*)offsets)[4 * t + 2] = make_int4(o[8], o[9], o[10], o[11]);
    ((int4*)offsets)[4 * t + 3] = make_int4(o[12], o[13], o[14], o[15]);
    if (t == 1023) offsets[NKEY] = NE;
}

// fill 8-byte entries at deterministic bases
__global__ __launch_bounds__(1024) void k_fillB(const int* __restrict__ smap,
                                                const float* __restrict__ wts,
                                                const int* __restrict__ priv,
                                                const int* __restrict__ offsets,
                                                const unsigned* __restrict__ hdr,
                                                int2* __restrict__ entries) {
    __shared__ int cur[NKEY];
    const int b = blockIdx.x;
    const int t = threadIdx.x;
    for (int i = t; i < NKEY; i += 1024) cur[i] = offsets[i] + priv[b * NKEY + i];
    __syncthreads();
    const int e0 = b * EPB;
    for (int i = 0; i < EPB / 1024; ++i) {      // 18
        const int e = e0 + i * 1024 + t;
        const int n = smap[e];
        const int o = e / 36;                   // e = o*36 + k*4 + p_tap
        const int r = e - o * 36;
        const int k = r >> 2;
        const unsigned h = hdr[(size_t)o * KK + k];
        const int st = (int)(h & 0xFFFFu);      // padded start (<= 791)
        const int cn = (int)(h >> 16);          // 1..512
        const unsigned wb = (__float_as_uint(wts[e]) + 0x8000u) >> 16;  // bf16 rn
        const int pos = atomicAdd(&cur[n >> 4], 1);
        entries[pos] = make_int2((o << 16) | ((n & 15) << 12) | ((cn - 1) << 2),
                                 (int)((wb << 16) | (unsigned)st));
    }
}

// ---------- entry decode ----------
#define DECODE(e, o, nl, cn, st, w)                         \
    const int o  = ((unsigned)(e).x) >> 16;                 \
    const int nl = ((e).x >> 12) & 15;                      \
    const int cn = (((e).x >> 2) & 511) + 1;                \
    const int st = (e).y & 0xFFFF;                          \
    const float w = __uint_as_float(((unsigned)(e).y >> 16) << 16);

// ============================================================================
// Gather v7: block = one 16-n chunk x 512 planes (32 KB acc, 4 blocks/CU).
// HALF-WAVE streams: each 32-lane group owns an entry stream (16 per block).
// Aligned runs: cn<=64 run = exactly 2 line fills. 3-deep pipeline per stream:
// A (xk arrived -> compute), B (xk in flight), C (entry in flight).
// ============================================================================
#define SWZ(p, nl) ((p) ^ ((nl) << 1))
__global__ __launch_bounds__(GTH, 8) void k_gather7(const int* __restrict__ offsets,
                                                    const int2* __restrict__ entries,
                                                    const unsigned* __restrict__ xk,
                                                    float* __restrict__ out) {
    __shared__ float acc[CHUNK * NPLANES];       // 32 KB
    const int bid = blockIdx.x;
    const int c = (bid & 7) * (NCHUNKS / 8) + (bid >> 3);   // XCD-contiguous
    const int tid = threadIdx.x;
    const int l32 = tid & 31;
    const int sid = tid >> 5;                    // 0..15 stream id

    f4_t* a4 = (f4_t*)acc;
    for (int i = tid; i < CHUNK * NPLANES / 4; i += GTH) a4[i] = (f4_t){0.f, 0.f, 0.f, 0.f};
    __syncthreads();

    const int j1 = offsets[c + 1];
    int jA = offsets[c] + sid;

    int2 eA = {0, 0}, eB = {0, 0}, eC = {0, 0};
    unsigned xA0 = 0, xA1 = 0, xB0 = 0, xB1 = 0;

    if (jA < j1) eA = entries[jA];
    int jB = jA + NS;
    if (jB < j1) eB = entries[jB];
    if (jA < j1) {
        DECODE(eA, o, nl, cn, st, w)
        const unsigned* r = xk + (size_t)o * XSTRIDE + st;
        if (l32 < cn)      xA0 = r[l32];
        if (l32 + 32 < cn) xA1 = r[l32 + 32];
    }
    if (jB < j1) {
        DECODE(eB, o, nl, cn, st, w)
        const unsigned* r = xk + (size_t)o * XSTRIDE + st;
        if (l32 < cn)      xB0 = r[l32];
        if (l32 + 32 < cn) xB1 = r[l32 + 32];
    }
    int jC = jB + NS;
    if (jC < j1) eC = entries[jC];

    while (jA < j1) {
        // issue xk for C (entry arrived last iter); prefetch entry D
        unsigned xC0 = 0, xC1 = 0;
        if (jC < j1) {
            DECODE(eC, o, nl, cn, st, w)
            const unsigned* r = xk + (size_t)o * XSTRIDE + st;
            if (l32 < cn)      xC0 = r[l32];
            if (l32 + 32 < cn) xC1 = r[l32 + 32];
        }
        const int jD = jC + NS;
        int2 eD = {0, 0};
        if (jD < j1) eD = entries[jD];

        // compute A
        {
            DECODE(eA, o, nl, cn, st, w)
            if (l32 < cn)
                atomicAdd(&acc[(nl << 9) + SWZ((int)(xA0 & 511), nl)],
                          w * __uint_as_float(xA0 & 0xFFFFFE00u));
            if (l32 + 32 < cn)
                atomicAdd(&acc[(nl << 9) + SWZ((int)(xA1 & 511), nl)],
                          w * __uint_as_float(xA1 & 0xFFFFFE00u));
            if (cn > 64) {
                const unsigned* r = xk + (size_t)o * XSTRIDE + st;
                for (int bb = l32 + 64; bb < cn; bb += 32) {
                    unsigned u = r[bb];
                    atomicAdd(&acc[(nl << 9) + SWZ((int)(u & 511), nl)],
                              w * __uint_as_float(u & 0xFFFFFE00u));
                }
            }
        }
        // rotate pipeline
        eA = eB; xA0 = xB0; xA1 = xB1; jA = jB;
        eB = eC; xB0 = xC0; xB1 = xC1; jB = jC;
        eC = eD; jC = jD;
    }
    __syncthreads();

    // flush: thread -> (p = i>>2, nl quad); LDS <=2-way, stores float4
    const int n0 = c << 4;
    for (int i = tid; i < CHUNK * NPLANES / 4; i += GTH) {
        const int p = i >> 2;
        const int nl = (i & 3) << 2;
        float4 v;
        v.x = acc[((nl + 0) << 9) + SWZ(p, nl + 0)];
        v.y = acc[((nl + 1) << 9) + SWZ(p, nl + 1)];
        v.z = acc[((nl + 2) << 9) + SWZ(p, nl + 2)];
        v.w = acc[((nl + 3) << 9) + SWZ(p, nl + 3)];
        *(float4*)(out + (size_t)p * N_IN + n0 + nl) = v;
    }
}

// ============================================================================
// Fallback (ws too small): atomic scatter
// ============================================================================
__global__ __launch_bounds__(256) void zero_kernel(float4* __restrict__ out, int n4) {
    int i = blockIdx.x * blockDim.x + threadIdx.x;
    int stride = gridDim.x * blockDim.x;
    const float4 z = {0.f, 0.f, 0.f, 0.f};
    for (; i < n4; i += stride) out[i] = z;
}

__global__ __launch_bounds__(256) void scatter_kernel(
    const float* __restrict__ x, const int* __restrict__ idx_mask,
    const int4* __restrict__ smap, const float4* __restrict__ wts,
    float* __restrict__ out)
{
    const int plane = blockIdx.x >> 8;
    const int o = ((blockIdx.x & 255) << 8) + threadIdx.x;
    const long ibase = (long)plane * N_OUT + o;
    const float xv = x[ibase];
    const int k = idx_mask[ibase];
    const int row = o * KK + k;
    const int4 m = smap[row];
    const float4 w = wts[row];
    float* op = out + (long)plane * N_IN;
    atomicAdd(op + m.x, w.x * xv);
    atomicAdd(op + m.y, w.y * xv);
    atomicAdd(op + m.z, w.z * xv);
    atomicAdd(op + m.w, w.w * xv);
}

// ============================================================================
extern "C" void kernel_launch(void* const* d_in, const int* in_sizes, int n_in,
                              void* d_out, int out_size, void* d_ws, size_t ws_size,
                              hipStream_t stream) {
    const float* x    = (const float*)d_in[0];
    const int*   idx  = (const int*)d_in[1];
    const int*   smap = (const int*)d_in[2];
    const float* wts  = (const float*)d_in[3];
    float* out = (float*)d_out;

    if (ws_size < (size_t)WS_END * 4) {
        zero_kernel<<<4096, 256, 0, stream>>>((float4*)out, out_size / 4);
        scatter_kernel<<<NPLANES * (N_OUT / 256), 256, 0, stream>>>(
            x, idx, (const int4*)smap, (const float4*)wts, out);
        return;
    }

    int* ws = (int*)d_ws;
    int* offsets   = ws + WS_OFFSETS;
    int* tot       = ws + WS_TOT;
    int* priv      = ws + WS_PRIV;
    unsigned* hdr  = (unsigned*)(ws + WS_HDR);
    int2* entries  = (int2*)(ws + WS_ENTR);
    unsigned* xk   = (unsigned*)(ws + WS_XK);

    // build
    k_xk<<<N_OUT / XKTILE, 256, 0, stream>>>(x, idx, xk, hdr);
    k_histA<<<NFB, 1024, 0, stream>>>(smap, priv);
    k_colscan<<<16, 1024, 0, stream>>>(priv, tot);
    k_scan16k<<<1, 1024, 0, stream>>>(tot, offsets);
    k_fillB<<<NFB, 1024, 0, stream>>>(smap, wts, priv, offsets, hdr, entries);

    // gather: one block per 16-n chunk, all 512 planes
    k_gather7<<<NCHUNKS, GTH, 0, stream>>>(offsets, entries, xk, out);
}

// Round 12
// 966.026 us; speedup vs baseline: 1.2667x; 1.0833x over previous
//
#include <hip/hip_runtime.h>

// x:              [B, C, N_OUT]  f32   (512 planes x 65536)
// idx_mask:       [B, C, N_OUT]  i32 in [0, K)
// sample_map:     [N_OUT, K, P]  i32 in [0, N_IN)
// interp_weights: [N_OUT, K, P]  f32
// out:            [B, C, N_IN]   f32
#define BB      8
#define CC      64
#define N_OUT   65536
#define N_IN    262144
#define KK      9
#define PP      4
#define NE      (N_OUT * KK * PP)   // 2,359,296
#define NPLANES 512
#define CHUNK   16                  // n per gather block (32 KB acc)
#define NCHUNKS (N_IN / CHUNK)      // 16384
#define NKEY    NCHUNKS
#define GTH     512                 // gather threads (8 waves, 16 half-wave streams)
#define NS      (GTH / 32)          // 16 entry streams per block
#define NFB     256                 // fill/hist blocks (1 fill block per CU)
#define EPB     (NE / NFB)          // 9216 entries per build block (< 65536 -> u16 hist ok)

typedef float f4_t __attribute__((ext_vector_type(4)));

// ---------------- d_ws layout (int units) ----------------
// entries int2: e.x = (o<<16)|(nl<<12)|((cnt-1)<<2) ; e.y = (w_bf16<<16)|start
// xk rows: compact, stride 512 u32 (2 KB per o). start <= 511.
#define WS_OFFSETS 0
#define WS_TOT     16400
#define WS_PRIV    32784
#define WS_HDR     (32784 + NFB * NKEY)           // 4227088
#define WS_ENTR    (4227088 + N_OUT * KK)         // 4816912 (8B aligned)
#define WS_XK      (4816912 + 2 * NE)             // 9535504
#define WS_END     (9535504 + N_OUT * 512)        // 43,089,936 ints (~164.4 MiB)

// ============================================================================
// k_xk (compact, r9 version): per o, sort the 512 planes' x by idx_mask tap k.
//   xk[o*512 + j] (k-sorted) = (x_bits & 0xFFFFFE00) | plane_id (9 bits)
//   hdr[o*9+k] = start | (cnt << 16)   (compact start, <= 511)
// ============================================================================
#define XKTILE 16
#define XPAD   520
__global__ __launch_bounds__(256) void k_xk(const float* __restrict__ x,
                                            const int*   __restrict__ idx,
                                            unsigned* __restrict__ xk,
                                            unsigned* __restrict__ hdr) {
    __shared__ float xs[XKTILE * XPAD];          // 33.3 KB
    __shared__ unsigned char ks[XKTILE * XPAD];  // 8.3 KB
    __shared__ unsigned ot[XKTILE * 512];        // 32 KB out tile
    __shared__ int cnt[XKTILE][12];
    __shared__ int cur[XKTILE][12];
    const int t = threadIdx.x;
    const int obase = blockIdx.x * XKTILE;

    for (int i = t; i < XKTILE * 12; i += 256) cnt[i / 12][i % 12] = 0;

    for (int i = t; i < 512 * (XKTILE / 4); i += 256) {   // 2048
        int p = i >> 2, q = i & 3;
        const size_t g = (size_t)p * N_OUT + obase + 4 * q;
        float4 xv = *(const float4*)(x + g);
        int4   kv = *(const int4*)(idx + g);
        int b = (4 * q) * XPAD + p;
        xs[b] = xv.x; xs[b + XPAD] = xv.y; xs[b + 2 * XPAD] = xv.z; xs[b + 3 * XPAD] = xv.w;
        ks[b] = (unsigned char)kv.x; ks[b + XPAD] = (unsigned char)kv.y;
        ks[b + 2 * XPAD] = (unsigned char)kv.z; ks[b + 3 * XPAD] = (unsigned char)kv.w;
    }
    __syncthreads();
    for (int i = t; i < XKTILE * 512; i += 256) {
        int oo = i >> 9, p = i & 511;
        atomicAdd(&cnt[oo][ks[oo * XPAD + p]], 1);
    }
    __syncthreads();
    if (t < XKTILE) {
        int s = 0;
        for (int k = 0; k < KK; ++k) {
            int c = cnt[t][k];
            cur[t][k] = s;
            hdr[(size_t)(obase + t) * KK + k] = (unsigned)(s | (c << 16));
            s += c;
        }
    }
    __syncthreads();
    for (int i = t; i < XKTILE * 512; i += 256) {
        int oo = i >> 9, p = i & 511;
        int k = ks[oo * XPAD + p];
        int pos = atomicAdd(&cur[oo][k], 1);
        unsigned xb = __float_as_uint(xs[oo * XPAD + p]);
        ot[(oo << 9) + pos] = (xb & 0xFFFFFE00u) | (unsigned)p;
    }
    __syncthreads();
    for (int i = t; i < XKTILE * 128; i += 256) {
        int oo = i >> 7, c4 = i & 127;
        ((int4*)(xk + (((size_t)(obase + oo)) << 9)))[c4] = ((const int4*)(ot + (oo << 9)))[c4];
    }
}

// ============================================================================
// Build: deterministic counting sort over 16384 chunk keys, no global atomics.
// Histogram packed as u16 pairs in u32 (32 KB LDS -> 4 blocks/CU), 256 blocks.
// ============================================================================
__global__ __launch_bounds__(1024) void k_histA(const int* __restrict__ smap,
                                                int* __restrict__ priv) {
    __shared__ unsigned h32[NKEY / 2];           // 32 KB, two u16 counters per u32
    const int b = blockIdx.x;
    const int t = threadIdx.x;
    for (int i = t; i < NKEY / 2; i += 1024) h32[i] = 0u;
    __syncthreads();
    const int e0 = b * EPB;
    #pragma unroll 3
    for (int i = 0; i < EPB / 1024; ++i) {       // 9
        const int key = smap[e0 + i * 1024 + t] >> 4;
        atomicAdd(&h32[key >> 1], 1u << ((key & 1) << 4));   // max 9216 < 65536, no carry
    }
    __syncthreads();
    for (int i = t; i < NKEY; i += 1024)
        priv[b * NKEY + i] = (int)((h32[i >> 1] >> ((i & 1) << 4)) & 0xFFFFu);
}

// 16384 parallel column scans (one key per thread) over 256 build blocks
__global__ __launch_bounds__(1024) void k_colscan(int* __restrict__ priv,
                                                  int* __restrict__ tot) {
    const int key = blockIdx.x * 1024 + threadIdx.x;
    int run = 0;
    for (int b = 0; b < NFB; ++b) {
        int* p = priv + b * NKEY + key;
        int v = *p; *p = run; run += v;
    }
    tot[key] = run;
}

__global__ __launch_bounds__(1024) void k_scan16k(const int* __restrict__ tot,
                                                  int* __restrict__ offsets) {
    __shared__ int sw[1024];
    const int t = threadIdx.x;
    int4 q0 = ((const int4*)tot)[4 * t + 0];
    int4 q1 = ((const int4*)tot)[4 * t + 1];
    int4 q2 = ((const int4*)tot)[4 * t + 2];
    int4 q3 = ((const int4*)tot)[4 * t + 3];
    int vals[16] = {q0.x, q0.y, q0.z, q0.w, q1.x, q1.y, q1.z, q1.w,
                    q2.x, q2.y, q2.z, q2.w, q3.x, q3.y, q3.z, q3.w};
    int s = 0;
    #pragma unroll
    for (int i = 0; i < 16; ++i) s += vals[i];
    sw[t] = s;
    __syncthreads();
    for (int off = 1; off < 1024; off <<= 1) {
        int v = (t >= off) ? sw[t - off] : 0;
        __syncthreads();
        sw[t] += v;
        __syncthreads();
    }
    int run = sw[t] - s;
    int o[16];
    #pragma unroll
    for (int i = 0; i < 16; ++i) { o[i] = run; run += vals[i]; }
    ((int4*)offsets)[4 * t + 0] = make_int4(o[0], o[1], o[2], o[3]);
    ((int4*)offsets)[4 * t + 1] = make_int4(o[4], o[5], o[6], o[7]);
    ((int4*)offsets)[4 * t + 2] = make_int4(o[8], o[9], o[10], o[11]);
    ((int4*)offsets)[4 * t + 3] = make_int4(o[12], o[13], o[14], o[15]);
    if (t == 1023) offsets[NKEY] = NE;
}

// fill 8-byte entries at deterministic bases; 256 blocks (one per CU)
__global__ __launch_bounds__(1024) void k_fillB(const int* __restrict__ smap,
                                                const float* __restrict__ wts,
                                                const int* __restrict__ priv,
                                                const int* __restrict__ offsets,
                                                const unsigned* __restrict__ hdr,
                                                int2* __restrict__ entries) {
    __shared__ int cur[NKEY];                    // 64 KB
    const int b = blockIdx.x;
    const int t = threadIdx.x;
    for (int i = t; i < NKEY; i += 1024) cur[i] = offsets[i] + priv[b * NKEY + i];
    __syncthreads();
    const int e0 = b * EPB;
    #pragma unroll 3
    for (int i = 0; i < EPB / 1024; ++i) {      // 9
        const int e = e0 + i * 1024 + t;
        const int n = smap[e];
        const int o = e / 36;                   // e = o*36 + k*4 + p_tap
        const int r = e - o * 36;
        const int k = r >> 2;
        const unsigned h = hdr[(size_t)o * KK + k];
        const int st = (int)(h & 0xFFFFu);      // compact start (<= 511)
        const int cn = (int)(h >> 16);          // 1..512
        const unsigned wb = (__float_as_uint(wts[e]) + 0x8000u) >> 16;  // bf16 rn
        const int pos = atomicAdd(&cur[n >> 4], 1);
        entries[pos] = make_int2((o << 16) | ((n & 15) << 12) | ((cn - 1) << 2),
                                 (int)((wb << 16) | (unsigned)st));
    }
}

// ---------- entry decode ----------
#define DECODE(e, o, nl, cn, st, w)                         \
    const int o  = ((unsigned)(e).x) >> 16;                 \
    const int nl = ((e).x >> 12) & 15;                      \
    const int cn = (((e).x >> 2) & 511) + 1;                \
    const int st = (e).y & 0xFFFF;                          \
    const float w = __uint_as_float(((unsigned)(e).y >> 16) << 16);

// ============================================================================
// Gather (r11 structure, compact xk stride 512): block = one 16-n chunk x 512
// planes (32 KB acc). 16 half-wave streams, 3-deep pipeline.
// ============================================================================
#define SWZ(p, nl) ((p) ^ ((nl) << 1))
__global__ __launch_bounds__(GTH, 8) void k_gather7(const int* __restrict__ offsets,
                                                    const int2* __restrict__ entries,
                                                    const unsigned* __restrict__ xk,
                                                    float* __restrict__ out) {
    __shared__ float acc[CHUNK * NPLANES];       // 32 KB
    const int bid = blockIdx.x;
    const int c = (bid & 7) * (NCHUNKS / 8) + (bid >> 3);   // XCD-contiguous
    const int tid = threadIdx.x;
    const int l32 = tid & 31;
    const int sid = tid >> 5;                    // 0..15 stream id

    f4_t* a4 = (f4_t*)acc;
    for (int i = tid; i < CHUNK * NPLANES / 4; i += GTH) a4[i] = (f4_t){0.f, 0.f, 0.f, 0.f};
    __syncthreads();

    const int j1 = offsets[c + 1];
    int jA = offsets[c] + sid;

    int2 eA = {0, 0}, eB = {0, 0}, eC = {0, 0};
    unsigned xA0 = 0, xA1 = 0, xB0 = 0, xB1 = 0;

    if (jA < j1) eA = entries[jA];
    int jB = jA + NS;
    if (jB < j1) eB = entries[jB];
    if (jA < j1) {
        DECODE(eA, o, nl, cn, st, w)
        const unsigned* r = xk + ((size_t)o << 9) + st;
        if (l32 < cn)      xA0 = r[l32];
        if (l32 + 32 < cn) xA1 = r[l32 + 32];
    }
    if (jB < j1) {
        DECODE(eB, o, nl, cn, st, w)
        const unsigned* r = xk + ((size_t)o << 9) + st;
        if (l32 < cn)      xB0 = r[l32];
        if (l32 + 32 < cn) xB1 = r[l32 + 32];
    }
    int jC = jB + NS;
    if (jC < j1) eC = entries[jC];

    while (jA < j1) {
        // issue xk for C (entry arrived last iter); prefetch entry D
        unsigned xC0 = 0, xC1 = 0;
        if (jC < j1) {
            DECODE(eC, o, nl, cn, st, w)
            const unsigned* r = xk + ((size_t)o << 9) + st;
            if (l32 < cn)      xC0 = r[l32];
            if (l32 + 32 < cn) xC1 = r[l32 + 32];
        }
        const int jD = jC + NS;
        int2 eD = {0, 0};
        if (jD < j1) eD = entries[jD];

        // compute A
        {
            DECODE(eA, o, nl, cn, st, w)
            if (l32 < cn)
                atomicAdd(&acc[(nl << 9) + SWZ((int)(xA0 & 511), nl)],
                          w * __uint_as_float(xA0 & 0xFFFFFE00u));
            if (l32 + 32 < cn)
                atomicAdd(&acc[(nl << 9) + SWZ((int)(xA1 & 511), nl)],
                          w * __uint_as_float(xA1 & 0xFFFFFE00u));
            if (cn > 64) {
                const unsigned* r = xk + ((size_t)o << 9) + st;
                for (int bb = l32 + 64; bb < cn; bb += 32) {
                    unsigned u = r[bb];
                    atomicAdd(&acc[(nl << 9) + SWZ((int)(u & 511), nl)],
                              w * __uint_as_float(u & 0xFFFFFE00u));
                }
            }
        }
        // rotate pipeline
        eA = eB; xA0 = xB0; xA1 = xB1; jA = jB;
        eB = eC; xB0 = xC0; xB1 = xC1; jB = jC;
        eC = eD; jC = jD;
    }
    __syncthreads();

    // flush: thread -> (p = i>>2, nl quad); LDS <=2-way, float4 stores
    const int n0 = c << 4;
    for (int i = tid; i < CHUNK * NPLANES / 4; i += GTH) {
        const int p = i >> 2;
        const int nl = (i & 3) << 2;
        float4 v;
        v.x = acc[((nl + 0) << 9) + SWZ(p, nl + 0)];
        v.y = acc[((nl + 1) << 9) + SWZ(p, nl + 1)];
        v.z = acc[((nl + 2) << 9) + SWZ(p, nl + 2)];
        v.w = acc[((nl + 3) << 9) + SWZ(p, nl + 3)];
        *(float4*)(out + (size_t)p * N_IN + n0 + nl) = v;
    }
}

// ============================================================================
// Fallback (ws too small): atomic scatter
// ============================================================================
__global__ __launch_bounds__(256) void zero_kernel(float4* __restrict__ out, int n4) {
    int i = blockIdx.x * blockDim.x + threadIdx.x;
    int stride = gridDim.x * blockDim.x;
    const float4 z = {0.f, 0.f, 0.f, 0.f};
    for (; i < n4; i += stride) out[i] = z;
}

__global__ __launch_bounds__(256) void scatter_kernel(
    const float* __restrict__ x, const int* __restrict__ idx_mask,
    const int4* __restrict__ smap, const float4* __restrict__ wts,
    float* __restrict__ out)
{
    const int plane = blockIdx.x >> 8;
    const int o = ((blockIdx.x & 255) << 8) + threadIdx.x;
    const long ibase = (long)plane * N_OUT + o;
    const float xv = x[ibase];
    const int k = idx_mask[ibase];
    const int row = o * KK + k;
    const int4 m = smap[row];
    const float4 w = wts[row];
    float* op = out + (long)plane * N_IN;
    atomicAdd(op + m.x, w.x * xv);
    atomicAdd(op + m.y, w.y * xv);
    atomicAdd(op + m.z, w.z * xv);
    atomicAdd(op + m.w, w.w * xv);
}

// ============================================================================
extern "C" void kernel_launch(void* const* d_in, const int* in_sizes, int n_in,
                              void* d_out, int out_size, void* d_ws, size_t ws_size,
                              hipStream_t stream) {
    const float* x    = (const float*)d_in[0];
    const int*   idx  = (const int*)d_in[1];
    const int*   smap = (const int*)d_in[2];
    const float* wts  = (const float*)d_in[3];
    float* out = (float*)d_out;

    if (ws_size < (size_t)WS_END * 4) {
        zero_kernel<<<4096, 256, 0, stream>>>((float4*)out, out_size / 4);
        scatter_kernel<<<NPLANES * (N_OUT / 256), 256, 0, stream>>>(
            x, idx, (const int4*)smap, (const float4*)wts, out);
        return;
    }

    int* ws = (int*)d_ws;
    int* offsets   = ws + WS_OFFSETS;
    int* tot       = ws + WS_TOT;
    int* priv      = ws + WS_PRIV;
    unsigned* hdr  = (unsigned*)(ws + WS_HDR);
    int2* entries  = (int2*)(ws + WS_ENTR);
    unsigned* xk   = (unsigned*)(ws + WS_XK);

    // build
    k_xk<<<N_OUT / XKTILE, 256, 0, stream>>>(x, idx, xk, hdr);
    k_histA<<<NFB, 1024, 0, stream>>>(smap, priv);
    k_colscan<<<16, 1024, 0, stream>>>(priv, tot);
    k_scan16k<<<1, 1024, 0, stream>>>(tot, offsets);
    k_fillB<<<NFB, 1024, 0, stream>>>(smap, wts, priv, offsets, hdr, entries);

    // gather: one block per 16-n chunk, all 512 planes
    k_gather7<<<NCHUNKS, GTH, 0, stream>>>(offsets, entries, xk, out);
}

// Round 13
// 956.974 us; speedup vs baseline: 1.2786x; 1.0095x over previous
//
#include <hip/hip_runtime.h>

// x:              [B, C, N_OUT]  f32   (512 planes x 65536)
// idx_mask:       [B, C, N_OUT]  i32 in [0, K)
// sample_map:     [N_OUT, K, P]  i32 in [0, N_IN)
// interp_weights: [N_OUT, K, P]  f32
// out:            [B, C, N_IN]   f32
#define BB      8
#define CC      64
#define N_OUT   65536
#define N_IN    262144
#define KK      9
#define PP      4
#define NE      (N_OUT * KK * PP)   // 2,359,296
#define NPLANES 512
#define CHUNK   32                  // n per gather block (64 KB acc, full-line flush)
#define NCHUNKS (N_IN / CHUNK)      // 8192
#define NKEY    NCHUNKS
#define GTH     512                 // 8 waves, 16 half-wave streams
#define NS      (GTH / 32)          // 16 entry streams per block
#define NFB     256                 // build blocks (1 per CU)
#define EPB     (NE / NFB)          // 9216 (< 65536 -> u16 hist ok)
#define ENT_STAGE 512               // staged entries per chunk (mean 288, 13 sigma)

typedef float f4_t __attribute__((ext_vector_type(4)));

// ---------------- d_ws layout (int units) ----------------
// entries int2: e.x = (o<<16)|(nl<<11)|((cnt-1)<<2) ; e.y = (w_bf16<<16)|start
// xk rows: compact, stride 512 u32 (2 KB per o). start <= 511.
#define WS_OFFSETS 0
#define WS_TOT     8208
#define WS_PRIV    16400
#define WS_HDR     (16400 + NFB * NKEY)           // 2113552
#define WS_ENTR    (2113552 + N_OUT * KK)         // 2703376
#define WS_XK      (2703376 + 2 * NE)             // 7421968
#define WS_END     (7421968 + N_OUT * 512)        // 40,976,400 ints (~156.3 MiB)

// ============================================================================
// k_xk: per o, sort the 512 planes' x by idx_mask tap k (compact runs).
//   xk[o*512 + j] = (x_bits & 0xFFFFFE00) | plane_id (9 bits)
//   hdr[o*9+k] = start | (cnt << 16)
// ============================================================================
#define XKTILE 16
#define XPAD   520
__global__ __launch_bounds__(256) void k_xk(const float* __restrict__ x,
                                            const int*   __restrict__ idx,
                                            unsigned* __restrict__ xk,
                                            unsigned* __restrict__ hdr) {
    __shared__ float xs[XKTILE * XPAD];
    __shared__ unsigned char ks[XKTILE * XPAD];
    __shared__ unsigned ot[XKTILE * 512];
    __shared__ int cnt[XKTILE][12];
    __shared__ int cur[XKTILE][12];
    const int t = threadIdx.x;
    const int obase = blockIdx.x * XKTILE;

    for (int i = t; i < XKTILE * 12; i += 256) cnt[i / 12][i % 12] = 0;

    for (int i = t; i < 512 * (XKTILE / 4); i += 256) {
        int p = i >> 2, q = i & 3;
        const size_t g = (size_t)p * N_OUT + obase + 4 * q;
        float4 xv = *(const float4*)(x + g);
        int4   kv = *(const int4*)(idx + g);
        int b = (4 * q) * XPAD + p;
        xs[b] = xv.x; xs[b + XPAD] = xv.y; xs[b + 2 * XPAD] = xv.z; xs[b + 3 * XPAD] = xv.w;
        ks[b] = (unsigned char)kv.x; ks[b + XPAD] = (unsigned char)kv.y;
        ks[b + 2 * XPAD] = (unsigned char)kv.z; ks[b + 3 * XPAD] = (unsigned char)kv.w;
    }
    __syncthreads();
    for (int i = t; i < XKTILE * 512; i += 256) {
        int oo = i >> 9, p = i & 511;
        atomicAdd(&cnt[oo][ks[oo * XPAD + p]], 1);
    }
    __syncthreads();
    if (t < XKTILE) {
        int s = 0;
        for (int k = 0; k < KK; ++k) {
            int c = cnt[t][k];
            cur[t][k] = s;
            hdr[(size_t)(obase + t) * KK + k] = (unsigned)(s | (c << 16));
            s += c;
        }
    }
    __syncthreads();
    for (int i = t; i < XKTILE * 512; i += 256) {
        int oo = i >> 9, p = i & 511;
        int k = ks[oo * XPAD + p];
        int pos = atomicAdd(&cur[oo][k], 1);
        unsigned xb = __float_as_uint(xs[oo * XPAD + p]);
        ot[(oo << 9) + pos] = (xb & 0xFFFFFE00u) | (unsigned)p;
    }
    __syncthreads();
    for (int i = t; i < XKTILE * 128; i += 256) {
        int oo = i >> 7, c4 = i & 127;
        ((int4*)(xk + (((size_t)(obase + oo)) << 9)))[c4] = ((const int4*)(ot + (oo << 9)))[c4];
    }
}

// ============================================================================
// Build: deterministic counting sort over 8192 chunk keys, no global atomics.
// ============================================================================
__global__ __launch_bounds__(1024) void k_histA(const int* __restrict__ smap,
                                                int* __restrict__ priv) {
    __shared__ unsigned h32[NKEY / 2];           // 16 KB, two u16 counters per u32
    const int b = blockIdx.x;
    const int t = threadIdx.x;
    for (int i = t; i < NKEY / 2; i += 1024) h32[i] = 0u;
    __syncthreads();
    const int e0 = b * EPB;
    #pragma unroll 3
    for (int i = 0; i < EPB / 1024; ++i) {       // 9
        const int key = smap[e0 + i * 1024 + t] >> 5;
        atomicAdd(&h32[key >> 1], 1u << ((key & 1) << 4));
    }
    __syncthreads();
    for (int i = t; i < NKEY; i += 1024)
        priv[b * NKEY + i] = (int)((h32[i >> 1] >> ((i & 1) << 4)) & 0xFFFFu);
}

__global__ __launch_bounds__(1024) void k_colscan(int* __restrict__ priv,
                                                  int* __restrict__ tot) {
    const int key = blockIdx.x * 1024 + threadIdx.x;
    int run = 0;
    for (int b = 0; b < NFB; ++b) {
        int* p = priv + b * NKEY + key;
        int v = *p; *p = run; run += v;
    }
    tot[key] = run;
}

__global__ __launch_bounds__(1024) void k_scan8k(const int* __restrict__ counts,
                                                 int* __restrict__ offsets) {
    __shared__ int sw[1024];
    const int t = threadIdx.x;
    int4 a = ((const int4*)counts)[2 * t];
    int4 b = ((const int4*)counts)[2 * t + 1];
    int s = a.x + a.y + a.z + a.w + b.x + b.y + b.z + b.w;
    sw[t] = s;
    __syncthreads();
    for (int off = 1; off < 1024; off <<= 1) {
        int v = (t >= off) ? sw[t - off] : 0;
        __syncthreads();
        sw[t] += v;
        __syncthreads();
    }
    int run = sw[t] - s;
    int vals[8] = {a.x, a.y, a.z, a.w, b.x, b.y, b.z, b.w};
    int o[8];
    #pragma unroll
    for (int q = 0; q < 8; ++q) { o[q] = run; run += vals[q]; }
    ((int4*)offsets)[2 * t]     = make_int4(o[0], o[1], o[2], o[3]);
    ((int4*)offsets)[2 * t + 1] = make_int4(o[4], o[5], o[6], o[7]);
    if (t == 1023) offsets[NKEY] = NE;
}

// fill 8-byte entries at deterministic bases; nl is 5 bits now (CHUNK=32)
__global__ __launch_bounds__(1024) void k_fillB(const int* __restrict__ smap,
                                                const float* __restrict__ wts,
                                                const int* __restrict__ priv,
                                                const int* __restrict__ offsets,
                                                const unsigned* __restrict__ hdr,
                                                int2* __restrict__ entries) {
    __shared__ int cur[NKEY];                    // 32 KB
    const int b = blockIdx.x;
    const int t = threadIdx.x;
    for (int i = t; i < NKEY; i += 1024) cur[i] = offsets[i] + priv[b * NKEY + i];
    __syncthreads();
    const int e0 = b * EPB;
    #pragma unroll 3
    for (int i = 0; i < EPB / 1024; ++i) {      // 9
        const int e = e0 + i * 1024 + t;
        const int n = smap[e];
        const int o = e / 36;                   // e = o*36 + k*4 + p_tap
        const int r = e - o * 36;
        const int k = r >> 2;
        const unsigned h = hdr[(size_t)o * KK + k];
        const int st = (int)(h & 0xFFFFu);      // compact start (<= 511)
        const int cn = (int)(h >> 16);          // 1..512
        const unsigned wb = (__float_as_uint(wts[e]) + 0x8000u) >> 16;  // bf16 rn
        const int pos = atomicAdd(&cur[n >> 5], 1);
        entries[pos] = make_int2((o << 16) | ((n & 31) << 11) | ((cn - 1) << 2),
                                 (int)((wb << 16) | (unsigned)st));
    }
}

// ---------- entry decode ----------
#define DECODE(e, o, nl, cn, st, w)                         \
    const int o  = ((unsigned)(e).x) >> 16;                 \
    const int nl = ((e).x >> 11) & 31;                      \
    const int cn = (((e).x >> 2) & 511) + 1;                \
    const int st = (e).y & 0xFFFF;                          \
    const float w = __uint_as_float(((unsigned)(e).y >> 16) << 16);

__device__ __forceinline__ int2 get_ent(const int2* __restrict__ gent,
                                        const int2* __restrict__ lent, int j) {
    return (j < ENT_STAGE) ? lent[j] : gent[j];
}

// ============================================================================
// Gather v8: block = one 32-n chunk x 512 planes (64 KB acc, 2 blocks/CU).
// Entries staged ONCE in LDS (coalesced). 16 half-wave streams, 3-deep xk
// pipeline. Flush = full 128B lines per plane, NONTEMPORAL -> output never
// allocates in L2/L3, keeping the 128 MB xk array L3-resident.
// ============================================================================
#define SWZ(p, nl) ((p) ^ (nl))
__global__ __launch_bounds__(GTH, 4) void k_gather8(const int* __restrict__ offsets,
                                                    const int2* __restrict__ entries,
                                                    const unsigned* __restrict__ xk,
                                                    float* __restrict__ out) {
    __shared__ float acc[CHUNK * NPLANES];       // 64 KB
    __shared__ int2 ent[ENT_STAGE];              // 4 KB
    const int bid = blockIdx.x;
    const int c = (bid & 7) * (NCHUNKS / 8) + (bid >> 3);   // XCD-contiguous
    const int tid = threadIdx.x;
    const int l32 = tid & 31;
    const int sid = tid >> 5;                    // 0..15 stream id

    f4_t* a4 = (f4_t*)acc;
    for (int i = tid; i < CHUNK * NPLANES / 4; i += GTH) a4[i] = (f4_t){0.f, 0.f, 0.f, 0.f};

    const int j0 = offsets[c];
    const int j1 = offsets[c + 1];
    const int je = j1 - j0;
    const int2* gent = entries + j0;
    {   // stage entries (coalesced int reads)
        const int n2 = min(je, ENT_STAGE) * 2;
        const int* src = (const int*)gent;
        int* dst = (int*)ent;
        for (int i = tid; i < n2; i += GTH) dst[i] = __builtin_nontemporal_load(src + i);
    }
    __syncthreads();

    int jA = sid;
    int2 eA = {0, 0}, eB = {0, 0};
    unsigned xA0 = 0, xA1 = 0, xB0 = 0, xB1 = 0;

    if (jA < je) {
        eA = get_ent(gent, ent, jA);
        DECODE(eA, o, nl, cn, st, w)
        const unsigned* r = xk + ((size_t)o << 9) + st;
        if (l32 < cn)      xA0 = r[l32];
        if (l32 + 32 < cn) xA1 = r[l32 + 32];
    }
    int jB = jA + NS;
    if (jB < je) {
        eB = get_ent(gent, ent, jB);
        DECODE(eB, o, nl, cn, st, w)
        const unsigned* r = xk + ((size_t)o << 9) + st;
        if (l32 < cn)      xB0 = r[l32];
        if (l32 + 32 < cn) xB1 = r[l32 + 32];
    }
    int jC = jB + NS;

    while (jA < je) {
        // issue xk for C
        unsigned xC0 = 0, xC1 = 0;
        int2 eC = {0, 0};
        if (jC < je) {
            eC = get_ent(gent, ent, jC);
            DECODE(eC, o, nl, cn, st, w)
            const unsigned* r = xk + ((size_t)o << 9) + st;
            if (l32 < cn)      xC0 = r[l32];
            if (l32 + 32 < cn) xC1 = r[l32 + 32];
        }
        // compute A
        {
            DECODE(eA, o, nl, cn, st, w)
            if (l32 < cn)
                atomicAdd(&acc[(nl << 9) + SWZ((int)(xA0 & 511), nl)],
                          w * __uint_as_float(xA0 & 0xFFFFFE00u));
            if (l32 + 32 < cn)
                atomicAdd(&acc[(nl << 9) + SWZ((int)(xA1 & 511), nl)],
                          w * __uint_as_float(xA1 & 0xFFFFFE00u));
            if (cn > 64) {
                const unsigned* r = xk + ((size_t)o << 9) + st;
                for (int bb = l32 + 64; bb < cn; bb += 32) {
                    unsigned u = r[bb];
                    atomicAdd(&acc[(nl << 9) + SWZ((int)(u & 511), nl)],
                              w * __uint_as_float(u & 0xFFFFFE00u));
                }
            }
        }
        // rotate
        eA = eB; xA0 = xB0; xA1 = xB1; jA = jB;
        eB = eC; xB0 = xC0; xB1 = xC1; jB = jC;
        jC += NS;
    }
    __syncthreads();

    // flush: 8 threads cover one full 128B plane line; NONTEMPORAL float4.
    // LDS read banks: (p^nl)&31 spreads ~2-way across the wave (free).
    const int n0 = c << 5;
    for (int i = tid; i < CHUNK * NPLANES / 4; i += GTH) {
        const int p = i >> 3;
        const int nl = (i & 7) << 2;
        f4_t v;
        v.x = acc[((nl + 0) << 9) + SWZ(p, nl + 0)];
        v.y = acc[((nl + 1) << 9) + SWZ(p, nl + 1)];
        v.z = acc[((nl + 2) << 9) + SWZ(p, nl + 2)];
        v.w = acc[((nl + 3) << 9) + SWZ(p, nl + 3)];
        __builtin_nontemporal_store(v, (f4_t*)(out + (size_t)p * N_IN + n0 + nl));
    }
}

// ============================================================================
// Fallback (ws too small): atomic scatter
// ============================================================================
__global__ __launch_bounds__(256) void zero_kernel(float4* __restrict__ out, int n4) {
    int i = blockIdx.x * blockDim.x + threadIdx.x;
    int stride = gridDim.x * blockDim.x;
    const float4 z = {0.f, 0.f, 0.f, 0.f};
    for (; i < n4; i += stride) out[i] = z;
}

__global__ __launch_bounds__(256) void scatter_kernel(
    const float* __restrict__ x, const int* __restrict__ idx_mask,
    const int4* __restrict__ smap, const float4* __restrict__ wts,
    float* __restrict__ out)
{
    const int plane = blockIdx.x >> 8;
    const int o = ((blockIdx.x & 255) << 8) + threadIdx.x;
    const long ibase = (long)plane * N_OUT + o;
    const float xv = x[ibase];
    const int k = idx_mask[ibase];
    const int row = o * KK + k;
    const int4 m = smap[row];
    const float4 w = wts[row];
    float* op = out + (long)plane * N_IN;
    atomicAdd(op + m.x, w.x * xv);
    atomicAdd(op + m.y, w.y * xv);
    atomicAdd(op + m.z, w.z * xv);
    atomicAdd(op + m.w, w.w * xv);
}

// ============================================================================
extern "C" void kernel_launch(void* const* d_in, const int* in_sizes, int n_in,
                              void* d_out, int out_size, void* d_ws, size_t ws_size,
                              hipStream_t stream) {
    const float* x    = (const float*)d_in[0];
    const int*   idx  = (const int*)d_in[1];
    const int*   smap = (const int*)d_in[2];
    const float* wts  = (const float*)d_in[3];
    float* out = (float*)d_out;

    if (ws_size < (size_t)WS_END * 4) {
        zero_kernel<<<4096, 256, 0, stream>>>((float4*)out, out_size / 4);
        scatter_kernel<<<NPLANES * (N_OUT / 256), 256, 0, stream>>>(
            x, idx, (const int4*)smap, (const float4*)wts, out);
        return;
    }

    int* ws = (int*)d_ws;
    int* offsets   = ws + WS_OFFSETS;
    int* tot       = ws + WS_TOT;
    int* priv      = ws + WS_PRIV;
    unsigned* hdr  = (unsigned*)(ws + WS_HDR);
    int2* entries  = (int2*)(ws + WS_ENTR);
    unsigned* xk   = (unsigned*)(ws + WS_XK);

    // build
    k_xk<<<N_OUT / XKTILE, 256, 0, stream>>>(x, idx, xk, hdr);
    k_histA<<<NFB, 1024, 0, stream>>>(smap, priv);
    k_colscan<<<8, 1024, 0, stream>>>(priv, tot);
    k_scan8k<<<1, 1024, 0, stream>>>(tot, offsets);
    k_fillB<<<NFB, 1024, 0, stream>>>(smap, wts, priv, offsets, hdr, entries);

    // gather: one block per 32-n chunk, all 512 planes
    k_gather8<<<NCHUNKS, GTH, 0, stream>>>(offsets, entries, xk, out);
}

// Round 14
// 931.660 us; speedup vs baseline: 1.3134x; 1.0272x over previous
//
#include <hip/hip_runtime.h>

// x:              [B, C, N_OUT]  f32   (512 planes x 65536)
// idx_mask:       [B, C, N_OUT]  i32 in [0, K)
// sample_map:     [N_OUT, K, P]  i32 in [0, N_IN)
// interp_weights: [N_OUT, K, P]  f32
// out:            [B, C, N_IN]   f32
#define BB      8
#define CC      64
#define N_OUT   65536
#define N_IN    262144
#define KK      9
#define PP      4
#define NE      (N_OUT * KK * PP)   // 2,359,296
#define NPLANES 512
#define CHUNK   32                  // n per gather block (64 KB acc, full-line flush)
#define NCHUNKS (N_IN / CHUNK)      // 8192
#define NKEY    NCHUNKS
#define GTH     512                 // 8 waves, 16 half-wave streams
#define NS      (GTH / 32)          // 16 entry streams per block
#define NFB     256                 // build blocks (1 per CU)
#define EPB     (NE / NFB)          // 9216 (< 65536 -> u16 hist ok)
#define ENT_STAGE 512               // staged entries per chunk (mean 288, 13 sigma)

typedef float f4_t __attribute__((ext_vector_type(4)));

// ---------------- d_ws layout (int units) ----------------
// entries int2: e.x = (o<<16)|(nl<<11)|((cnt-1)<<2) ; e.y = (w_bf16<<16)|start
// xk rows: compact, stride 512 u32 (2 KB per o). start <= 511.
#define WS_OFFSETS 0
#define WS_TOT     8208
#define WS_PRIV    16400
#define WS_HDR     (16400 + NFB * NKEY)           // 2113552
#define WS_ENTR    (2113552 + N_OUT * KK)         // 2703376
#define WS_XK      (2703376 + 2 * NE)             // 7421968
#define WS_END     (7421968 + N_OUT * 512)        // 40,976,400 ints (~156.3 MiB)

// ============================================================================
// k_xk: per o, sort the 512 planes' x by idx_mask tap k (compact runs).
//   xk[o*512 + j] = (x_bits & 0xFFFFFE00) | plane_id (9 bits)
//   hdr[o*9+k] = start | (cnt << 16)
// XCD-contiguous o-mapping: consecutive-o blocks run temporally adjacent on
// the SAME XCD, so the 128 B x/idx lines spanning two blocks' 64 B halves are
// L2-shared instead of being fetched twice from HBM (2x fetch reduction).
// ============================================================================
#define XKTILE 16
#define XPAD   520
__global__ __launch_bounds__(256) void k_xk(const float* __restrict__ x,
                                            const int*   __restrict__ idx,
                                            unsigned* __restrict__ xk,
                                            unsigned* __restrict__ hdr) {
    __shared__ float xs[XKTILE * XPAD];
    __shared__ unsigned char ks[XKTILE * XPAD];
    __shared__ unsigned ot[XKTILE * 512];
    __shared__ int cnt[XKTILE][12];
    __shared__ int cur[XKTILE][12];
    const int t = threadIdx.x;
    // grid = 4096 blocks; xcd = bid&7 owns a contiguous 8192-o region.
    const int bid = blockIdx.x;
    const int obase = ((bid & 7) * 512 + (bid >> 3)) * XKTILE;

    for (int i = t; i < XKTILE * 12; i += 256) cnt[i / 12][i % 12] = 0;

    for (int i = t; i < 512 * (XKTILE / 4); i += 256) {
        int p = i >> 2, q = i & 3;
        const size_t g = (size_t)p * N_OUT + obase + 4 * q;
        float4 xv = *(const float4*)(x + g);
        int4   kv = *(const int4*)(idx + g);
        int b = (4 * q) * XPAD + p;
        xs[b] = xv.x; xs[b + XPAD] = xv.y; xs[b + 2 * XPAD] = xv.z; xs[b + 3 * XPAD] = xv.w;
        ks[b] = (unsigned char)kv.x; ks[b + XPAD] = (unsigned char)kv.y;
        ks[b + 2 * XPAD] = (unsigned char)kv.z; ks[b + 3 * XPAD] = (unsigned char)kv.w;
    }
    __syncthreads();
    for (int i = t; i < XKTILE * 512; i += 256) {
        int oo = i >> 9, p = i & 511;
        atomicAdd(&cnt[oo][ks[oo * XPAD + p]], 1);
    }
    __syncthreads();
    if (t < XKTILE) {
        int s = 0;
        for (int k = 0; k < KK; ++k) {
            int c = cnt[t][k];
            cur[t][k] = s;
            hdr[(size_t)(obase + t) * KK + k] = (unsigned)(s | (c << 16));
            s += c;
        }
    }
    __syncthreads();
    for (int i = t; i < XKTILE * 512; i += 256) {
        int oo = i >> 9, p = i & 511;
        int k = ks[oo * XPAD + p];
        int pos = atomicAdd(&cur[oo][k], 1);
        unsigned xb = __float_as_uint(xs[oo * XPAD + p]);
        ot[(oo << 9) + pos] = (xb & 0xFFFFFE00u) | (unsigned)p;
    }
    __syncthreads();
    for (int i = t; i < XKTILE * 128; i += 256) {
        int oo = i >> 7, c4 = i & 127;
        ((int4*)(xk + (((size_t)(obase + oo)) << 9)))[c4] = ((const int4*)(ot + (oo << 9)))[c4];
    }
}

// ============================================================================
// Build: deterministic counting sort over 8192 chunk keys, no global atomics.
// ============================================================================
__global__ __launch_bounds__(1024) void k_histA(const int* __restrict__ smap,
                                                int* __restrict__ priv) {
    __shared__ unsigned h32[NKEY / 2];           // 16 KB, two u16 counters per u32
    const int b = blockIdx.x;
    const int t = threadIdx.x;
    for (int i = t; i < NKEY / 2; i += 1024) h32[i] = 0u;
    __syncthreads();
    const int e0 = b * EPB;
    #pragma unroll 3
    for (int i = 0; i < EPB / 1024; ++i) {       // 9
        const int key = smap[e0 + i * 1024 + t] >> 5;
        atomicAdd(&h32[key >> 1], 1u << ((key & 1) << 4));
    }
    __syncthreads();
    for (int i = t; i < NKEY; i += 1024)
        priv[b * NKEY + i] = (int)((h32[i >> 1] >> ((i & 1) << 4)) & 0xFFFFu);
}

__global__ __launch_bounds__(1024) void k_colscan(int* __restrict__ priv,
                                                  int* __restrict__ tot) {
    const int key = blockIdx.x * 1024 + threadIdx.x;
    int run = 0;
    for (int b = 0; b < NFB; ++b) {
        int* p = priv + b * NKEY + key;
        int v = *p; *p = run; run += v;
    }
    tot[key] = run;
}

__global__ __launch_bounds__(1024) void k_scan8k(const int* __restrict__ counts,
                                                 int* __restrict__ offsets) {
    __shared__ int sw[1024];
    const int t = threadIdx.x;
    int4 a = ((const int4*)counts)[2 * t];
    int4 b = ((const int4*)counts)[2 * t + 1];
    int s = a.x + a.y + a.z + a.w + b.x + b.y + b.z + b.w;
    sw[t] = s;
    __syncthreads();
    for (int off = 1; off < 1024; off <<= 1) {
        int v = (t >= off) ? sw[t - off] : 0;
        __syncthreads();
        sw[t] += v;
        __syncthreads();
    }
    int run = sw[t] - s;
    int vals[8] = {a.x, a.y, a.z, a.w, b.x, b.y, b.z, b.w};
    int o[8];
    #pragma unroll
    for (int q = 0; q < 8; ++q) { o[q] = run; run += vals[q]; }
    ((int4*)offsets)[2 * t]     = make_int4(o[0], o[1], o[2], o[3]);
    ((int4*)offsets)[2 * t + 1] = make_int4(o[4], o[5], o[6], o[7]);
    if (t == 1023) offsets[NKEY] = NE;
}

// fill 8-byte entries at deterministic bases; nl is 5 bits (CHUNK=32)
__global__ __launch_bounds__(1024) void k_fillB(const int* __restrict__ smap,
                                                const float* __restrict__ wts,
                                                const int* __restrict__ priv,
                                                const int* __restrict__ offsets,
                                                const unsigned* __restrict__ hdr,
                                                int2* __restrict__ entries) {
    __shared__ int cur[NKEY];                    // 32 KB
    const int b = blockIdx.x;
    const int t = threadIdx.x;
    for (int i = t; i < NKEY; i += 1024) cur[i] = offsets[i] + priv[b * NKEY + i];
    __syncthreads();
    const int e0 = b * EPB;
    #pragma unroll 3
    for (int i = 0; i < EPB / 1024; ++i) {      // 9
        const int e = e0 + i * 1024 + t;
        const int n = smap[e];
        const int o = e / 36;                   // e = o*36 + k*4 + p_tap
        const int r = e - o * 36;
        const int k = r >> 2;
        const unsigned h = hdr[(size_t)o * KK + k];
        const int st = (int)(h & 0xFFFFu);      // compact start (<= 511)
        const int cn = (int)(h >> 16);          // 1..512
        const unsigned wb = (__float_as_uint(wts[e]) + 0x8000u) >> 16;  // bf16 rn
        const int pos = atomicAdd(&cur[n >> 5], 1);
        entries[pos] = make_int2((o << 16) | ((n & 31) << 11) | ((cn - 1) << 2),
                                 (int)((wb << 16) | (unsigned)st));
    }
}

// ---------- entry decode ----------
#define DECODE(e, o, nl, cn, st, w)                         \
    const int o  = ((unsigned)(e).x) >> 16;                 \
    const int nl = ((e).x >> 11) & 31;                      \
    const int cn = (((e).x >> 2) & 511) + 1;                \
    const int st = (e).y & 0xFFFF;                          \
    const float w = __uint_as_float(((unsigned)(e).y >> 16) << 16);

__device__ __forceinline__ int2 get_ent(const int2* __restrict__ gent,
                                        const int2* __restrict__ lent, int j) {
    return (j < ENT_STAGE) ? lent[j] : gent[j];
}

// ============================================================================
// Gather (r13, unchanged — measured floor 733 us): block = one 32-n chunk x
// 512 planes (64 KB acc). Entries staged once in LDS; 16 half-wave streams,
// 3-deep xk pipeline; full-128B-line NT flush.
// ============================================================================
#define SWZ(p, nl) ((p) ^ (nl))
__global__ __launch_bounds__(GTH, 4) void k_gather8(const int* __restrict__ offsets,
                                                    const int2* __restrict__ entries,
                                                    const unsigned* __restrict__ xk,
                                                    float* __restrict__ out) {
    __shared__ float acc[CHUNK * NPLANES];       // 64 KB
    __shared__ int2 ent[ENT_STAGE];              // 4 KB
    const int bid = blockIdx.x;
    const int c = (bid & 7) * (NCHUNKS / 8) + (bid >> 3);   // XCD-contiguous
    const int tid = threadIdx.x;
    const int l32 = tid & 31;
    const int sid = tid >> 5;                    // 0..15 stream id

    f4_t* a4 = (f4_t*)acc;
    for (int i = tid; i < CHUNK * NPLANES / 4; i += GTH) a4[i] = (f4_t){0.f, 0.f, 0.f, 0.f};

    const int j0 = offsets[c];
    const int j1 = offsets[c + 1];
    const int je = j1 - j0;
    const int2* gent = entries + j0;
    {   // stage entries (coalesced int reads)
        const int n2 = min(je, ENT_STAGE) * 2;
        const int* src = (const int*)gent;
        int* dst = (int*)ent;
        for (int i = tid; i < n2; i += GTH) dst[i] = __builtin_nontemporal_load(src + i);
    }
    __syncthreads();

    int jA = sid;
    int2 eA = {0, 0}, eB = {0, 0};
    unsigned xA0 = 0, xA1 = 0, xB0 = 0, xB1 = 0;

    if (jA < je) {
        eA = get_ent(gent, ent, jA);
        DECODE(eA, o, nl, cn, st, w)
        const unsigned* r = xk + ((size_t)o << 9) + st;
        if (l32 < cn)      xA0 = r[l32];
        if (l32 + 32 < cn) xA1 = r[l32 + 32];
    }
    int jB = jA + NS;
    if (jB < je) {
        eB = get_ent(gent, ent, jB);
        DECODE(eB, o, nl, cn, st, w)
        const unsigned* r = xk + ((size_t)o << 9) + st;
        if (l32 < cn)      xB0 = r[l32];
        if (l32 + 32 < cn) xB1 = r[l32 + 32];
    }
    int jC = jB + NS;

    while (jA < je) {
        // issue xk for C
        unsigned xC0 = 0, xC1 = 0;
        int2 eC = {0, 0};
        if (jC < je) {
            eC = get_ent(gent, ent, jC);
            DECODE(eC, o, nl, cn, st, w)
            const unsigned* r = xk + ((size_t)o << 9) + st;
            if (l32 < cn)      xC0 = r[l32];
            if (l32 + 32 < cn) xC1 = r[l32 + 32];
        }
        // compute A
        {
            DECODE(eA, o, nl, cn, st, w)
            if (l32 < cn)
                atomicAdd(&acc[(nl << 9) + SWZ((int)(xA0 & 511), nl)],
                          w * __uint_as_float(xA0 & 0xFFFFFE00u));
            if (l32 + 32 < cn)
                atomicAdd(&acc[(nl << 9) + SWZ((int)(xA1 & 511), nl)],
                          w * __uint_as_float(xA1 & 0xFFFFFE00u));
            if (cn > 64) {
                const unsigned* r = xk + ((size_t)o << 9) + st;
                for (int bb = l32 + 64; bb < cn; bb += 32) {
                    unsigned u = r[bb];
                    atomicAdd(&acc[(nl << 9) + SWZ((int)(u & 511), nl)],
                              w * __uint_as_float(u & 0xFFFFFE00u));
                }
            }
        }
        // rotate
        eA = eB; xA0 = xB0; xA1 = xB1; jA = jB;
        eB = eC; xB0 = xC0; xB1 = xC1; jB = jC;
        jC += NS;
    }
    __syncthreads();

    // flush: 8 threads cover one full 128B plane line; NT float4.
    const int n0 = c << 5;
    for (int i = tid; i < CHUNK * NPLANES / 4; i += GTH) {
        const int p = i >> 3;
        const int nl = (i & 7) << 2;
        f4_t v;
        v.x = acc[((nl + 0) << 9) + SWZ(p, nl + 0)];
        v.y = acc[((nl + 1) << 9) + SWZ(p, nl + 1)];
        v.z = acc[((nl + 2) << 9) + SWZ(p, nl + 2)];
        v.w = acc[((nl + 3) << 9) + SWZ(p, nl + 3)];
        __builtin_nontemporal_store(v, (f4_t*)(out + (size_t)p * N_IN + n0 + nl));
    }
}

// ============================================================================
// Fallback (ws too small): atomic scatter
// ============================================================================
__global__ __launch_bounds__(256) void zero_kernel(float4* __restrict__ out, int n4) {
    int i = blockIdx.x * blockDim.x + threadIdx.x;
    int stride = gridDim.x * blockDim.x;
    const float4 z = {0.f, 0.f, 0.f, 0.f};
    for (; i < n4; i += stride) out[i] = z;
}

__global__ __launch_bounds__(256) void scatter_kernel(
    const float* __restrict__ x, const int* __restrict__ idx_mask,
    const int4* __restrict__ smap, const float4* __restrict__ wts,
    float* __restrict__ out)
{
    const int plane = blockIdx.x >> 8;
    const int o = ((blockIdx.x & 255) << 8) + threadIdx.x;
    const long ibase = (long)plane * N_OUT + o;
    const float xv = x[ibase];
    const int k = idx_mask[ibase];
    const int row = o * KK + k;
    const int4 m = smap[row];
    const float4 w = wts[row];
    float* op = out + (long)plane * N_IN;
    atomicAdd(op + m.x, w.x * xv);
    atomicAdd(op + m.y, w.y * xv);
    atomicAdd(op + m.z, w.z * xv);
    atomicAdd(op + m.w, w.w * xv);
}

// ============================================================================
extern "C" void kernel_launch(void* const* d_in, const int* in_sizes, int n_in,
                              void* d_out, int out_size, void* d_ws, size_t ws_size,
                              hipStream_t stream) {
    const float* x    = (const float*)d_in[0];
    const int*   idx  = (const int*)d_in[1];
    const int*   smap = (const int*)d_in[2];
    const float* wts  = (const float*)d_in[3];
    float* out = (float*)d_out;

    if (ws_size < (size_t)WS_END * 4) {
        zero_kernel<<<4096, 256, 0, stream>>>((float4*)out, out_size / 4);
        scatter_kernel<<<NPLANES * (N_OUT / 256), 256, 0, stream>>>(
            x, idx, (const int4*)smap, (const float4*)wts, out);
        return;
    }

    int* ws = (int*)d_ws;
    int* offsets   = ws + WS_OFFSETS;
    int* tot       = ws + WS_TOT;
    int* priv      = ws + WS_PRIV;
    unsigned* hdr  = (unsigned*)(ws + WS_HDR);
    int2* entries  = (int2*)(ws + WS_ENTR);
    unsigned* xk   = (unsigned*)(ws + WS_XK);

    // build
    k_xk<<<N_OUT / XKTILE, 256, 0, stream>>>(x, idx, xk, hdr);
    k_histA<<<NFB, 1024, 0, stream>>>(smap, priv);
    k_colscan<<<8, 1024, 0, stream>>>(priv, tot);
    k_scan8k<<<1, 1024, 0, stream>>>(tot, offsets);
    k_fillB<<<NFB, 1024, 0, stream>>>(smap, wts, priv, offsets, hdr, entries);

    // gather: one block per 32-n chunk, all 512 planes
    k_gather8<<<NCHUNKS, GTH, 0, stream>>>(offsets, entries, xk, out);
}

// Round 15
// 920.747 us; speedup vs baseline: 1.3289x; 1.0119x over previous
//
#include <hip/hip_runtime.h>

// x:              [B, C, N_OUT]  f32   (512 planes x 65536)
// idx_mask:       [B, C, N_OUT]  i32 in [0, K)
// sample_map:     [N_OUT, K, P]  i32 in [0, N_IN)
// interp_weights: [N_OUT, K, P]  f32
// out:            [B, C, N_IN]   f32
#define BB      8
#define CC      64
#define N_OUT   65536
#define N_IN    262144
#define KK      9
#define PP      4
#define NE      (N_OUT * KK * PP)   // 2,359,296
#define NPLANES 512
#define CHUNK   32                  // n per gather block (64 KB acc, full-line flush)
#define NCHUNKS (N_IN / CHUNK)      // 8192
#define NKEY    NCHUNKS
#define GTH     512                 // 8 waves, 16 half-wave streams
#define NS      (GTH / 32)          // 16 entry streams per block
#define NFB     256                 // build blocks (1 per CU)
#define EPB     (NE / NFB)          // 9216 (< 65536 -> u16 hist ok)
#define ENT_STAGE 512               // staged entries per chunk (mean 288, 13 sigma)

typedef float f4_t __attribute__((ext_vector_type(4)));

// ---------------- d_ws layout (int units) ----------------
// entries int2: e.x = (o<<16)|(nl<<11)|((cnt-1)<<2) ; e.y = (w_bf16<<16)|start
// xk rows: compact, stride 512 u32 (2 KB per o). start <= 511.
#define WS_OFFSETS 0
#define WS_TOT     8208
#define WS_PRIV    16400
#define WS_HDR     (16400 + NFB * NKEY)           // 2113552
#define WS_ENTR    (2113552 + N_OUT * KK)         // 2703376
#define WS_XK      (2703376 + 2 * NE)             // 7421968
#define WS_END     (7421968 + N_OUT * 512)        // 40,976,400 ints (~156.3 MiB)

// ============================================================================
// k_xk: per o, sort the 512 planes' x by idx_mask tap k (compact runs).
//   xk[o*512 + j] = (x_bits & 0xFFFFFE00) | plane_id (9 bits)
//   hdr[o*9+k] = start | (cnt << 16)
// XCD-contiguous o-mapping (r14, kept): consecutive-o blocks are temporally
// adjacent on the SAME XCD -> split 128 B x/idx lines are L2-shared.
// r15: placement writes go DIRECTLY to global xk (4 B scatters confined to a
// 2 KB row fully dirtied by this block -> L2 write-combines to full lines).
// Drops the 32 KB ot tile + flush pass: LDS 75->43 KB, 2->3 blocks/CU.
// ============================================================================
#define XKTILE 16
#define XPAD   520
__global__ __launch_bounds__(256) void k_xk(const float* __restrict__ x,
                                            const int*   __restrict__ idx,
                                            unsigned* __restrict__ xk,
                                            unsigned* __restrict__ hdr) {
    __shared__ float xs[XKTILE * XPAD];          // 33.3 KB
    __shared__ unsigned char ks[XKTILE * XPAD];  // 8.3 KB
    __shared__ int cnt[XKTILE][12];
    __shared__ int cur[XKTILE][12];
    const int t = threadIdx.x;
    // grid = 4096 blocks; xcd = bid&7 owns a contiguous 8192-o region.
    const int bid = blockIdx.x;
    const int obase = ((bid & 7) * 512 + (bid >> 3)) * XKTILE;

    for (int i = t; i < XKTILE * 12; i += 256) cnt[i / 12][i % 12] = 0;

    for (int i = t; i < 512 * (XKTILE / 4); i += 256) {
        int p = i >> 2, q = i & 3;
        const size_t g = (size_t)p * N_OUT + obase + 4 * q;
        float4 xv = *(const float4*)(x + g);
        int4   kv = *(const int4*)(idx + g);
        int b = (4 * q) * XPAD + p;
        xs[b] = xv.x; xs[b + XPAD] = xv.y; xs[b + 2 * XPAD] = xv.z; xs[b + 3 * XPAD] = xv.w;
        ks[b] = (unsigned char)kv.x; ks[b + XPAD] = (unsigned char)kv.y;
        ks[b + 2 * XPAD] = (unsigned char)kv.z; ks[b + 3 * XPAD] = (unsigned char)kv.w;
    }
    __syncthreads();
    for (int i = t; i < XKTILE * 512; i += 256) {
        int oo = i >> 9, p = i & 511;
        atomicAdd(&cnt[oo][ks[oo * XPAD + p]], 1);
    }
    __syncthreads();
    if (t < XKTILE) {
        int s = 0;
        for (int k = 0; k < KK; ++k) {
            int c = cnt[t][k];
            cur[t][k] = s;
            hdr[(size_t)(obase + t) * KK + k] = (unsigned)(s | (c << 16));
            s += c;
        }
    }
    __syncthreads();
    // place: write k-sorted values directly to global xk (L2 merges the 4 B
    // scatters within each fully-written 2 KB row).
    for (int i = t; i < XKTILE * 512; i += 256) {
        int oo = i >> 9, p = i & 511;
        int k = ks[oo * XPAD + p];
        int pos = atomicAdd(&cur[oo][k], 1);
        unsigned xb = __float_as_uint(xs[oo * XPAD + p]);
        xk[((size_t)(obase + oo) << 9) + pos] = (xb & 0xFFFFFE00u) | (unsigned)p;
    }
}

// ============================================================================
// Build: deterministic counting sort over 8192 chunk keys, no global atomics.
// ============================================================================
__global__ __launch_bounds__(1024) void k_histA(const int* __restrict__ smap,
                                                int* __restrict__ priv) {
    __shared__ unsigned h32[NKEY / 2];           // 16 KB, two u16 counters per u32
    const int b = blockIdx.x;
    const int t = threadIdx.x;
    for (int i = t; i < NKEY / 2; i += 1024) h32[i] = 0u;
    __syncthreads();
    const int e0 = b * EPB;
    #pragma unroll 3
    for (int i = 0; i < EPB / 1024; ++i) {       // 9
        const int key = smap[e0 + i * 1024 + t] >> 5;
        atomicAdd(&h32[key >> 1], 1u << ((key & 1) << 4));
    }
    __syncthreads();
    for (int i = t; i < NKEY; i += 1024)
        priv[b * NKEY + i] = (int)((h32[i >> 1] >> ((i & 1) << 4)) & 0xFFFFu);
}

__global__ __launch_bounds__(1024) void k_colscan(int* __restrict__ priv,
                                                  int* __restrict__ tot) {
    const int key = blockIdx.x * 1024 + threadIdx.x;
    int run = 0;
    for (int b = 0; b < NFB; ++b) {
        int* p = priv + b * NKEY + key;
        int v = *p; *p = run; run += v;
    }
    tot[key] = run;
}

__global__ __launch_bounds__(1024) void k_scan8k(const int* __restrict__ counts,
                                                 int* __restrict__ offsets) {
    __shared__ int sw[1024];
    const int t = threadIdx.x;
    int4 a = ((const int4*)counts)[2 * t];
    int4 b = ((const int4*)counts)[2 * t + 1];
    int s = a.x + a.y + a.z + a.w + b.x + b.y + b.z + b.w;
    sw[t] = s;
    __syncthreads();
    for (int off = 1; off < 1024; off <<= 1) {
        int v = (t >= off) ? sw[t - off] : 0;
        __syncthreads();
        sw[t] += v;
        __syncthreads();
    }
    int run = sw[t] - s;
    int vals[8] = {a.x, a.y, a.z, a.w, b.x, b.y, b.z, b.w};
    int o[8];
    #pragma unroll
    for (int q = 0; q < 8; ++q) { o[q] = run; run += vals[q]; }
    ((int4*)offsets)[2 * t]     = make_int4(o[0], o[1], o[2], o[3]);
    ((int4*)offsets)[2 * t + 1] = make_int4(o[4], o[5], o[6], o[7]);
    if (t == 1023) offsets[NKEY] = NE;
}

// fill 8-byte entries at deterministic bases; nl is 5 bits (CHUNK=32)
__global__ __launch_bounds__(1024) void k_fillB(const int* __restrict__ smap,
                                                const float* __restrict__ wts,
                                                const int* __restrict__ priv,
                                                const int* __restrict__ offsets,
                                                const unsigned* __restrict__ hdr,
                                                int2* __restrict__ entries) {
    __shared__ int cur[NKEY];                    // 32 KB
    const int b = blockIdx.x;
    const int t = threadIdx.x;
    for (int i = t; i < NKEY; i += 1024) cur[i] = offsets[i] + priv[b * NKEY + i];
    __syncthreads();
    const int e0 = b * EPB;
    #pragma unroll 3
    for (int i = 0; i < EPB / 1024; ++i) {      // 9
        const int e = e0 + i * 1024 + t;
        const int n = smap[e];
        const int o = e / 36;                   // e = o*36 + k*4 + p_tap
        const int r = e - o * 36;
        const int k = r >> 2;
        const unsigned h = hdr[(size_t)o * KK + k];
        const int st = (int)(h & 0xFFFFu);      // compact start (<= 511)
        const int cn = (int)(h >> 16);          // 1..512
        const unsigned wb = (__float_as_uint(wts[e]) + 0x8000u) >> 16;  // bf16 rn
        const int pos = atomicAdd(&cur[n >> 5], 1);
        entries[pos] = make_int2((o << 16) | ((n & 31) << 11) | ((cn - 1) << 2),
                                 (int)((wb << 16) | (unsigned)st));
    }
}

// ---------- entry decode ----------
#define DECODE(e, o, nl, cn, st, w)                         \
    const int o  = ((unsigned)(e).x) >> 16;                 \
    const int nl = ((e).x >> 11) & 31;                      \
    const int cn = (((e).x >> 2) & 511) + 1;                \
    const int st = (e).y & 0xFFFF;                          \
    const float w = __uint_as_float(((unsigned)(e).y >> 16) << 16);

__device__ __forceinline__ int2 get_ent(const int2* __restrict__ gent,
                                        const int2* __restrict__ lent, int j) {
    return (j < ENT_STAGE) ? lent[j] : gent[j];
}

// ============================================================================
// Gather (frozen since r13 — measured transaction-rate floor 730 us):
// block = one 32-n chunk x 512 planes (64 KB acc). Entries staged once in
// LDS; 16 half-wave streams, 3-deep xk pipeline; full-128B-line NT flush.
// ============================================================================
#define SWZ(p, nl) ((p) ^ (nl))
__global__ __launch_bounds__(GTH, 4) void k_gather8(const int* __restrict__ offsets,
                                                    const int2* __restrict__ entries,
                                                    const unsigned* __restrict__ xk,
                                                    float* __restrict__ out) {
    __shared__ float acc[CHUNK * NPLANES];       // 64 KB
    __shared__ int2 ent[ENT_STAGE];              // 4 KB
    const int bid = blockIdx.x;
    const int c = (bid & 7) * (NCHUNKS / 8) + (bid >> 3);   // XCD-contiguous
    const int tid = threadIdx.x;
    const int l32 = tid & 31;
    const int sid = tid >> 5;                    // 0..15 stream id

    f4_t* a4 = (f4_t*)acc;
    for (int i = tid; i < CHUNK * NPLANES / 4; i += GTH) a4[i] = (f4_t){0.f, 0.f, 0.f, 0.f};

    const int j0 = offsets[c];
    const int j1 = offsets[c + 1];
    const int je = j1 - j0;
    const int2* gent = entries + j0;
    {   // stage entries (coalesced int reads)
        const int n2 = min(je, ENT_STAGE) * 2;
        const int* src = (const int*)gent;
        int* dst = (int*)ent;
        for (int i = tid; i < n2; i += GTH) dst[i] = __builtin_nontemporal_load(src + i);
    }
    __syncthreads();

    int jA = sid;
    int2 eA = {0, 0}, eB = {0, 0};
    unsigned xA0 = 0, xA1 = 0, xB0 = 0, xB1 = 0;

    if (jA < je) {
        eA = get_ent(gent, ent, jA);
        DECODE(eA, o, nl, cn, st, w)
        const unsigned* r = xk + ((size_t)o << 9) + st;
        if (l32 < cn)      xA0 = r[l32];
        if (l32 + 32 < cn) xA1 = r[l32 + 32];
    }
    int jB = jA + NS;
    if (jB < je) {
        eB = get_ent(gent, ent, jB);
        DECODE(eB, o, nl, cn, st, w)
        const unsigned* r = xk + ((size_t)o << 9) + st;
        if (l32 < cn)      xB0 = r[l32];
        if (l32 + 32 < cn) xB1 = r[l32 + 32];
    }
    int jC = jB + NS;

    while (jA < je) {
        // issue xk for C
        unsigned xC0 = 0, xC1 = 0;
        int2 eC = {0, 0};
        if (jC < je) {
            eC = get_ent(gent, ent, jC);
            DECODE(eC, o, nl, cn, st, w)
            const unsigned* r = xk + ((size_t)o << 9) + st;
            if (l32 < cn)      xC0 = r[l32];
            if (l32 + 32 < cn) xC1 = r[l32 + 32];
        }
        // compute A
        {
            DECODE(eA, o, nl, cn, st, w)
            if (l32 < cn)
                atomicAdd(&acc[(nl << 9) + SWZ((int)(xA0 & 511), nl)],
                          w * __uint_as_float(xA0 & 0xFFFFFE00u));
            if (l32 + 32 < cn)
                atomicAdd(&acc[(nl << 9) + SWZ((int)(xA1 & 511), nl)],
                          w * __uint_as_float(xA1 & 0xFFFFFE00u));
            if (cn > 64) {
                const unsigned* r = xk + ((size_t)o << 9) + st;
                for (int bb = l32 + 64; bb < cn; bb += 32) {
                    unsigned u = r[bb];
                    atomicAdd(&acc[(nl << 9) + SWZ((int)(u & 511), nl)],
                              w * __uint_as_float(u & 0xFFFFFE00u));
                }
            }
        }
        // rotate
        eA = eB; xA0 = xB0; xA1 = xB1; jA = jB;
        eB = eC; xB0 = xC0; xB1 = xC1; jB = jC;
        jC += NS;
    }
    __syncthreads();

    // flush: 8 threads cover one full 128B plane line; NT float4.
    const int n0 = c << 5;
    for (int i = tid; i < CHUNK * NPLANES / 4; i += GTH) {
        const int p = i >> 3;
        const int nl = (i & 7) << 2;
        f4_t v;
        v.x = acc[((nl + 0) << 9) + SWZ(p, nl + 0)];
        v.y = acc[((nl + 1) << 9) + SWZ(p, nl + 1)];
        v.z = acc[((nl + 2) << 9) + SWZ(p, nl + 2)];
        v.w = acc[((nl + 3) << 9) + SWZ(p, nl + 3)];
        __builtin_nontemporal_store(v, (f4_t*)(out + (size_t)p * N_IN + n0 + nl));
    }
}

// ============================================================================
// Fallback (ws too small): atomic scatter
// ============================================================================
__global__ __launch_bounds__(256) void zero_kernel(float4* __restrict__ out, int n4) {
    int i = blockIdx.x * blockDim.x + threadIdx.x;
    int stride = gridDim.x * blockDim.x;
    const float4 z = {0.f, 0.f, 0.f, 0.f};
    for (; i < n4; i += stride) out[i] = z;
}

__global__ __launch_bounds__(256) void scatter_kernel(
    const float* __restrict__ x, const int* __restrict__ idx_mask,
    const int4* __restrict__ smap, const float4* __restrict__ wts,
    float* __restrict__ out)
{
    const int plane = blockIdx.x >> 8;
    const int o = ((blockIdx.x & 255) << 8) + threadIdx.x;
    const long ibase = (long)plane * N_OUT + o;
    const float xv = x[ibase];
    const int k = idx_mask[ibase];
    const int row = o * KK + k;
    const int4 m = smap[row];
    const float4 w = wts[row];
    float* op = out + (long)plane * N_IN;
    atomicAdd(op + m.x, w.x * xv);
    atomicAdd(op + m.y, w.y * xv);
    atomicAdd(op + m.z, w.z * xv);
    atomicAdd(op + m.w, w.w * xv);
}

// ============================================================================
extern "C" void kernel_launch(void* const* d_in, const int* in_sizes, int n_in,
                              void* d_out, int out_size, void* d_ws, size_t ws_size,
                              hipStream_t stream) {
    const float* x    = (const float*)d_in[0];
    const int*   idx  = (const int*)d_in[1];
    const int*   smap = (const int*)d_in[2];
    const float* wts  = (const float*)d_in[3];
    float* out = (float*)d_out;

    if (ws_size < (size_t)WS_END * 4) {
        zero_kernel<<<4096, 256, 0, stream>>>((float4*)out, out_size / 4);
        scatter_kernel<<<NPLANES * (N_OUT / 256), 256, 0, stream>>>(
            x, idx, (const int4*)smap, (const float4*)wts, out);
        return;
    }

    int* ws = (int*)d_ws;
    int* offsets   = ws + WS_OFFSETS;
    int* tot       = ws + WS_TOT;
    int* priv      = ws + WS_PRIV;
    unsigned* hdr  = (unsigned*)(ws + WS_HDR);
    int2* entries  = (int2*)(ws + WS_ENTR);
    unsigned* xk   = (unsigned*)(ws + WS_XK);

    // build
    k_xk<<<N_OUT / XKTILE, 256, 0, stream>>>(x, idx, xk, hdr);
    k_histA<<<NFB, 1024, 0, stream>>>(smap, priv);
    k_colscan<<<8, 1024, 0, stream>>>(priv, tot);
    k_scan8k<<<1, 1024, 0, stream>>>(tot, offsets);
    k_fillB<<<NFB, 1024, 0, stream>>>(smap, wts, priv, offsets, hdr, entries);

    // gather: one block per 32-n chunk, all 512 planes
    k_gather8<<<NCHUNKS, GTH, 0, stream>>>(offsets, entries, xk, out);
}